// Round 9
// baseline (371.271 us; speedup 1.0000x reference)
//
#include <hip/hip_runtime.h>
#include <hip/hip_fp16.h>
#include <math.h>

#define B_    8
#define S_    8192
#define DIN   64
#define DM    256
#define NS    32
#define NL    4
#define PIPE  192            // pipeline tokens per block (64 warm + 128 out)
#define TOUT  128
#define NWARM 64
#define HIST  16             // scan window; a^17 <= 0.35^17 ~ 7e-9
#define NBLK  (B_ * S_ / TOUT)   // 512
#define NHALF 192            // threads per n-half (wave-aligned)

// ---- fp32 precomputed-weight offsets (Wf) ----
#define OFF_G   0            // [64][64]  in_w^T in_w
#define OFF_GX  4096         // [64]      in_w^T in_b
#define OFF_G0  4160         // [1]       ||in_b||^2 (pad to 4224)
#define OFF_WY  4224         // [4][64][32]  (Bws_l . in_w)^T  (c-major)
#define OFF_WU  12416        // [4][64][32]  (Cw_l^T in_w)^T   (c-major)
#define OFF_P   20608        // [6][32][32]  Bws_m.Cw_lp
#define OFF_R   26752        // [10][32][32] Cw_m^T Cw_lp
#define OFF_CY  36992        // [4][32]
#define OFF_CU  37120        // [4][32]
#define OFF_TX  37248        // [4][64]
#define OFF_TV  37504        // [10][32]
#define OFF_CT  37824        // [4]
#define OFF_CC  37828        // [4]
#define OFF_AV  37832        // [4][32]
#define PRE_N   37960

// ---- packed-fp16 weight offsets (Wh, u32 units) ----
#define HOFF_G   0           // [32][64]
#define HOFF_GX  2048        // [32]
#define HOFF_WY  2080        // [4][32][32]
#define HOFF_WU  6176        // [4][32][32]
#define HOFF_P   10272       // [6][16][32]
#define HOFF_R   13344       // [10][16][32]
#define HOFF_TX  18464       // [4][32]
#define HOFF_TV  18592       // [10][16]
#define WH_N     18752

#define WS_WH    40960       // float offset of Wh region in ws
#define WS_PART  65536       // float offset of part[512][193]

// ---- LDS layout (u32): Dbuf[192][17] | slot0..slot3 [192][17] | partial ----
#define SSTR      17
#define LOFF_PART 16320      // float[192][2]
#define LDSN      16704      // u32 -> 66,816 B -> 2 blocks/CU (grid-limited anyway)
#define PSTR      67         // reduce scratch stride (floats); 3jj+c -> conflict-free

typedef _Float16 h2_t __attribute__((ext_vector_type(2)));
typedef uint uv8  __attribute__((ext_vector_type(8)));    // per-layer s half
typedef uint uv32 __attribute__((ext_vector_type(32)));   // x (fp16 packed)

__device__ __forceinline__ float h2f(ushort u) { return __half2float(__ushort_as_half(u)); }
__device__ __forceinline__ ushort f2h(float f) { return __half_as_ushort(__float2half(f)); }
__device__ __forceinline__ void unpack2(uint w, float& a, float& b) {
  a = h2f((ushort)(w & 0xffffu)); b = h2f((ushort)(w >> 16));
}
__device__ __forceinline__ uint pack2(float a, float b) {
  return (uint)f2h(a) | ((uint)f2h(b) << 16);
}
__device__ __forceinline__ float fdot2h(uint w, uint v, float c) {
  return __builtin_amdgcn_fdot2(__builtin_bit_cast(h2_t, w),
                                __builtin_bit_cast(h2_t, v), c, false);
}

// acc[16] += (own n-half of) W.x  (W packed pairs over c, n-fast)
template<int H>
__device__ __forceinline__ void mv64half(const uint* __restrict__ Wp,
                                         uv32 xr, float acc[16]) {
  #pragma unroll 4
  for (int c2 = 0; c2 < 32; ++c2) {
    const uint xp = xr[c2];
    const uint* W0 = Wp + c2 * 32 + 16 * H;
    #pragma unroll
    for (int k = 0; k < 16; ++k) acc[k] = fdot2h(W0[k], xp, acc[k]);
  }
}
// acc[16] += (own n-half of) M.s, s = full packed LDS row
template<int H>
__device__ __forceinline__ void mv32half(const uint* __restrict__ Mp,
                                         const uint* __restrict__ srow, float acc[16]) {
  #pragma unroll
  for (int m2 = 0; m2 < 16; ++m2) {
    const uint sv = srow[m2];
    const uint* M0 = Mp + m2 * 32 + 16 * H;
    #pragma unroll
    for (int k = 0; k < 16; ++k) acc[k] = fdot2h(M0[k], sv, acc[k]);
  }
}
// own m-half of tv . s
template<int H>
__device__ __forceinline__ float tv8half(const uint* __restrict__ vp,
                                         const uint* __restrict__ srow, float c) {
  #pragma unroll
  for (int m2 = 0; m2 < 8; ++m2) c = fdot2h(vp[8*H + m2], srow[8*H + m2], c);
  return c;
}
__device__ __forceinline__ float dot_own(const float acc[16], uv8 s) {
  float t = 0.f;
  #pragma unroll
  for (int m = 0; m < 8; ++m) {
    float a, b; unpack2(s[m], a, b);
    t = fmaf(acc[2*m], a, t); t = fmaf(acc[2*m+1], b, t);
  }
  return t;
}

// ---------------------------------------------------------------------------
// Prep: fused fp32 matrices (identical to round-6..8, verified).
// ---------------------------------------------------------------------------
__global__ void ssm_prep(const float* __restrict__ in_w, const float* __restrict__ in_b,
                         const float* __restrict__ logA,
                         const float* __restrict__ Bw, const float* __restrict__ Cw,
                         const float* __restrict__ Cb, const float* __restrict__ nsc,
                         float* __restrict__ Wf)
{
  const int t = blockIdx.x * 256 + threadIdx.x;
  if (t >= PRE_N) return;
  const int pm6[6]  = {1,2,2,3,3,3}, pl6[6] = {0,0,1,0,1,2};
  const int rm10[10] = {0,1,1,2,2,2,3,3,3,3}, rl10[10] = {0,0,1,0,1,2,0,1,2,3};
  float s = 0.f;
  if (t < OFF_GX) {
    const int i = t >> 6, jj = t & 63;
    for (int d = 0; d < DM; ++d) s = fmaf(in_w[d*64 + i], in_w[d*64 + jj], s);
  } else if (t < OFF_G0) {
    const int i = t - OFF_GX;
    for (int d = 0; d < DM; ++d) s = fmaf(in_w[d*64 + i], in_b[d], s);
  } else if (t < OFF_WY) {
    if (t == OFF_G0) { for (int d = 0; d < DM; ++d) s = fmaf(in_b[d], in_b[d], s); }
  } else if (t < OFF_WU) {
    const int r = t - OFF_WY, l = r >> 11, q = r & 2047, c = q >> 5, n = q & 31;
    for (int d = 0; d < DM; ++d)
      s = fmaf(Bw[(l*NS + n)*DM + d] * nsc[l*DM + d], in_w[d*64 + c], s);
  } else if (t < OFF_P) {
    const int r = t - OFF_WU, l = r >> 11, q = r & 2047, c = q >> 5, n = q & 31;
    for (int d = 0; d < DM; ++d)
      s = fmaf(Cw[(l*DM + d)*NS + n], in_w[d*64 + c], s);
  } else if (t < OFF_R) {
    const int r = t - OFF_P, pi = r >> 10, q = r & 1023, np = q >> 5, n = q & 31;
    const int m = pm6[pi], lp = pl6[pi];
    for (int d = 0; d < DM; ++d)
      s = fmaf(Bw[(m*NS + n)*DM + d] * nsc[m*DM + d], Cw[(lp*DM + d)*NS + np], s);
  } else if (t < OFF_CY) {
    const int r = t - OFF_R, ri = r >> 10, q = r & 1023, np = q >> 5, n = q & 31;
    const int m = rm10[ri], lp = rl10[ri];
    for (int d = 0; d < DM; ++d)
      s = fmaf(Cw[(m*DM + d)*NS + n], Cw[(lp*DM + d)*NS + np], s);
  } else if (t < OFF_CU) {
    const int r = t - OFF_CY, l = r >> 5, n = r & 31;
    for (int d = 0; d < DM; ++d) {
      float bs = in_b[d];
      for (int lp = 0; lp < l; ++lp) bs += Cb[lp*DM + d];
      s = fmaf(Bw[(l*NS + n)*DM + d] * nsc[l*DM + d], bs, s);
    }
  } else if (t < OFF_TX) {
    const int r = t - OFF_CU, l = r >> 5, n = r & 31;
    for (int d = 0; d < DM; ++d) {
      float bs = in_b[d];
      for (int lp = 0; lp < l; ++lp) bs += Cb[lp*DM + d];
      s = fmaf(Cw[(l*DM + d)*NS + n], bs, s);
    }
  } else if (t < OFF_TV) {
    const int r = t - OFF_TX, l = r >> 6, i = r & 63;
    for (int d = 0; d < DM; ++d) s = fmaf(Cb[l*DM + d], in_w[d*64 + i], s);
  } else if (t < OFF_CT) {
    const int r = t - OFF_TV, vi = r >> 5, np = r & 31;
    const int m = rm10[vi], lp = rl10[vi];
    for (int d = 0; d < DM; ++d)
      s = fmaf(Cb[m*DM + d], Cw[(lp*DM + d)*NS + np], s);
  } else if (t < OFF_CC) {
    const int l = t - OFF_CT;
    for (int d = 0; d < DM; ++d) {
      float bs = in_b[d];
      for (int lp = 0; lp < l; ++lp) bs += Cb[lp*DM + d];
      s = fmaf(Cb[l*DM + d], bs, s);
    }
  } else if (t < OFF_AV) {
    const int l = t - OFF_CC;
    for (int d = 0; d < DM; ++d) s = fmaf(Cb[l*DM + d], Cb[l*DM + d], s);
  } else {
    s = 1.0f / (1.0f + expf(-logA[t - OFF_AV]));
  }
  Wf[t] = s;
}

// ---------------------------------------------------------------------------
// Pack: fp32 fused matrices -> fp16 pairs (identical to round-7/8, verified).
// ---------------------------------------------------------------------------
__global__ void ssm_pack(const float* __restrict__ Wf, uint* __restrict__ Wh)
{
  const int t = blockIdx.x * 256 + threadIdx.x;
  if (t >= WH_N) return;
  float a, b;
  if (t < HOFF_GX) {
    const int c2 = t >> 6, i = t & 63;
    a = Wf[OFF_G + (2*c2)*64 + i]; b = Wf[OFF_G + (2*c2+1)*64 + i];
  } else if (t < HOFF_WY) {
    const int c2 = t - HOFF_GX;
    a = Wf[OFF_GX + 2*c2]; b = Wf[OFF_GX + 2*c2 + 1];
  } else if (t < HOFF_WU) {
    const int r = t - HOFF_WY, l = r >> 10, q = r & 1023, c2 = q >> 5, n = q & 31;
    a = Wf[OFF_WY + l*2048 + (2*c2)*32 + n]; b = Wf[OFF_WY + l*2048 + (2*c2+1)*32 + n];
  } else if (t < HOFF_P) {
    const int r = t - HOFF_WU, l = r >> 10, q = r & 1023, c2 = q >> 5, n = q & 31;
    a = Wf[OFF_WU + l*2048 + (2*c2)*32 + n]; b = Wf[OFF_WU + l*2048 + (2*c2+1)*32 + n];
  } else if (t < HOFF_R) {
    const int r = t - HOFF_P, pi = r >> 9, q = r & 511, m2 = q >> 5, n = q & 31;
    a = Wf[OFF_P + pi*1024 + (2*m2)*32 + n]; b = Wf[OFF_P + pi*1024 + (2*m2+1)*32 + n];
  } else if (t < HOFF_TX) {
    const int r = t - HOFF_R, ri = r >> 9, q = r & 511, m2 = q >> 5, n = q & 31;
    a = Wf[OFF_R + ri*1024 + (2*m2)*32 + n]; b = Wf[OFF_R + ri*1024 + (2*m2+1)*32 + n];
  } else if (t < HOFF_TV) {
    const int r = t - HOFF_TX, l = r >> 5, c2 = r & 31;
    a = Wf[OFF_TX + l*64 + 2*c2]; b = Wf[OFF_TX + l*64 + 2*c2 + 1];
  } else {
    const int r = t - HOFF_TV, vi = r >> 4, m2 = r & 15;
    a = Wf[OFF_TV + vi*32 + 2*m2]; b = Wf[OFF_TV + vi*32 + 2*m2 + 1];
  }
  Wh[t] = pack2(a, b);
}

// ---------------------------------------------------------------------------
// Per-layer core, templated on layer L and n-half H. Returns own s-half.
// Barrier counts: L<3 -> 3, L==3 -> 4 (identical for H=0/1).
// ---------------------------------------------------------------------------
template<int L, int H>
__device__ __forceinline__ uv8 layer_core(
    const int tid, const int j, const int ltok, uint* lds,
    const float* __restrict__ Wf, const uint* __restrict__ Wh,
    const float* __restrict__ Bb, float& nq, uv32 xr)
{
  constexpr int RB = L * (L + 1) / 2;
  constexpr int PB = (L == 1) ? 0 : (L == 2) ? 1 : 3;
  uint* slotL = lds + 3264 * (L + 1);
  uint* Dslot = (L < 3) ? lds : slotL;
  float* partial = (float*)(lds + LOFF_PART);
  const float inv = 1.0f / (sqrtf(fmaxf(nq, 0.f)) * 0.0625f + 1e-8f);

  // ---- D = valid ? inv*y + Bb : 0 (own half) ----
  {
    float acc[16];
    #pragma unroll
    for (int k = 0; k < 16; ++k) acc[k] = Wf[OFF_CY + L*32 + 16*H + k];
    mv64half<H>(Wh + HOFF_WY + L*1024, xr, acc);
    if constexpr (L > 0) mv32half<H>(Wh + HOFF_P + (PB+0)*512, lds + 3264*1 + j*SSTR, acc);
    if constexpr (L > 1) mv32half<H>(Wh + HOFF_P + (PB+1)*512, lds + 3264*2 + j*SSTR, acc);
    if constexpr (L > 2) mv32half<H>(Wh + HOFF_P + (PB+2)*512, lds + 3264*3 + j*SSTR, acc);
    uint* drow = Dslot + j*SSTR + 8*H;
    const bool valid = (ltok >= 0);
    #pragma unroll
    for (int m = 0; m < 8; ++m) {
      const float v0 = valid ? fmaf(inv, acc[2*m],   Bb[L*32 + 16*H + 2*m])   : 0.f;
      const float v1 = valid ? fmaf(inv, acc[2*m+1], Bb[L*32 + 16*H + 2*m+1]) : 0.f;
      drow[m] = pack2(v0, v1);
    }
  }
  __syncthreads();

  uv8 sL;
  if constexpr (L < 3) {
    // windowed scan: thread (n = tid&31, tg = tid>>5 in [0,12)), 16 tokens each
    const int n = tid & 31, tg = tid >> 5;
    const float a = Wf[OFF_AV + L*32 + n];
    const ushort* dh = (const ushort*)lds;
    ushort* sh = (ushort*)slotL;
    float carry = 0.f;
    #pragma unroll
    for (int k = 0; k < HIST; ++k) {
      const int p = tg*16 - HIST + k;
      const float v = (p >= 0) ? h2f(dh[p*(2*SSTR) + n]) : 0.f;
      carry = fmaf(a, carry, v);
    }
    #pragma unroll
    for (int k = 0; k < 16; ++k) {
      const int p = tg*16 + k;
      carry = fmaf(a, carry, h2f(dh[p*(2*SSTR) + n]));
      sh[p*(2*SSTR) + n] = f2h(carry);
    }
    __syncthreads();
    #pragma unroll
    for (int m = 0; m < 8; ++m) sL[m] = slotL[j*SSTR + 8*H + m];
  } else {
    // layer 3: Horner FIR over D3 (slot3), own half; write s3 back after barrier
    float s3f[16];
    #pragma unroll
    for (int k = 0; k < 16; ++k) s3f[k] = 0.f;
    if (j >= NWARM) {
      #pragma unroll 1
      for (int lag = HIST; lag >= 0; --lag) {
        const uint* row = slotL + (j - lag)*SSTR + 8*H;
        #pragma unroll
        for (int m = 0; m < 8; ++m) {
          float v0, v1; unpack2(row[m], v0, v1);
          s3f[2*m]   = fmaf(Wf[OFF_AV + 96 + 16*H + 2*m],   s3f[2*m],   v0);
          s3f[2*m+1] = fmaf(Wf[OFF_AV + 96 + 16*H + 2*m+1], s3f[2*m+1], v1);
        }
      }
    }
    __syncthreads();   // all FIR reads of D3 complete
    {
      uint* srow = slotL + j*SSTR + 8*H;
      #pragma unroll
      for (int m = 0; m < 8; ++m) { sL[m] = pack2(s3f[2*m], s3f[2*m+1]); srow[m] = sL[m]; }
    }
    __syncthreads();   // s3 visible to partner half
  }

  // ---- nq update via half-partials ----
  {
    float acc2[16];
    #pragma unroll
    for (int k = 0; k < 16; ++k) acc2[k] = Wf[OFF_CU + L*32 + 16*H + k];
    mv64half<H>(Wh + HOFF_WU + L*1024, xr, acc2);
    float tl = (H == 0) ? Wf[OFF_CT + L] : 0.f;
    #pragma unroll
    for (int c2 = 0; c2 < 16; ++c2)
      tl = fdot2h(Wh[HOFF_TX + L*32 + 16*H + c2], xr[16*H + c2], tl);
    if constexpr (L > 0) { const uint* sr = lds + 3264*1 + j*SSTR;
      mv32half<H>(Wh + HOFF_R + (RB+0)*512, sr, acc2);
      tl = tv8half<H>(Wh + HOFF_TV + (RB+0)*16, sr, tl); }
    if constexpr (L > 1) { const uint* sr = lds + 3264*2 + j*SSTR;
      mv32half<H>(Wh + HOFF_R + (RB+1)*512, sr, acc2);
      tl = tv8half<H>(Wh + HOFF_TV + (RB+1)*16, sr, tl); }
    if constexpr (L > 2) { const uint* sr = lds + 3264*3 + j*SSTR;
      mv32half<H>(Wh + HOFF_R + (RB+2)*512, sr, acc2);
      tl = tv8half<H>(Wh + HOFF_TV + (RB+2)*16, sr, tl); }
    const float us = dot_own(acc2, sL);
    float acc3[16];
    #pragma unroll
    for (int k = 0; k < 16; ++k) acc3[k] = 0.f;
    const uint* sself = slotL + j*SSTR;
    mv32half<H>(Wh + HOFF_R + (RB+L)*512, sself, acc3);
    const float rss = dot_own(acc3, sL);
    const float qs = tv8half<H>(Wh + HOFF_TV + (RB+L)*16, sself, 0.f);
    partial[2*j + H] = 2.f*(us + tl) + rss + 2.f*qs + ((H == 0) ? Wf[OFF_CC + L] : 0.f);
    __syncthreads();
    nq += partial[2*j] + partial[2*j + 1];
  }
  return sL;
}

// ---------------------------------------------------------------------------
// Whole-thread body, templated on n-half H (wave-uniform dispatch).
// ---------------------------------------------------------------------------
template<int H>
__device__ __forceinline__ void main_body(
    const float* __restrict__ x, const float* __restrict__ Wf,
    const uint* __restrict__ Wh, const float* __restrict__ Bb,
    float* __restrict__ part, uint* lds)
{
  const int tid = threadIdx.x;
  const int j = tid - H * NHALF;
  const int blk = blockIdx.x;
  const int bb = blk >> 6;
  const int s0base = (blk & 63) * TOUT;
  const int ltok = s0base - NWARM + j;
  float* partial = (float*)(lds + LOFF_PART);

  // x -> registers (fp16 packed, 32 u32)
  uv32 xr;
  if (ltok >= 0) {
    const float4* xg4 = (const float4*)(x + ((size_t)bb * S_ + (size_t)ltok) * DIN);
    #pragma unroll
    for (int c4 = 0; c4 < 16; ++c4) {
      const float4 v = xg4[c4];
      xr[2*c4] = pack2(v.x, v.y); xr[2*c4+1] = pack2(v.z, v.w);
    }
  } else {
    #pragma unroll
    for (int m = 0; m < 32; ++m) xr[m] = 0u;
  }

  // nq0 = g0 + 2 gx.x + x^T G x, via half-partials
  float nq;
  {
    float a2[32];
    #pragma unroll
    for (int i = 0; i < 32; ++i) a2[i] = 0.f;
    #pragma unroll 4
    for (int c2 = 0; c2 < 32; ++c2) {
      const uint xp = xr[c2];
      const uint* G0 = Wh + HOFF_G + c2*64 + 32*H;
      #pragma unroll
      for (int i = 0; i < 32; ++i) a2[i] = fdot2h(G0[i], xp, a2[i]);
    }
    float hd = 0.f;
    #pragma unroll
    for (int ii = 0; ii < 16; ++ii) {
      float xa, xb; unpack2(xr[16*H + ii], xa, xb);
      hd = fmaf(xa, a2[2*ii], hd); hd = fmaf(xb, a2[2*ii+1], hd);
    }
    float gx = 0.f;
    #pragma unroll
    for (int c2 = 0; c2 < 16; ++c2)
      gx = fdot2h(Wh[HOFF_GX + 16*H + c2], xr[16*H + c2], gx);
    partial[2*j + H] = hd + 2.f*gx + ((H == 0) ? Wf[OFF_G0] : 0.f);
    __syncthreads();
    nq = partial[2*j] + partial[2*j + 1];
  }

  const uv8 s0r = layer_core<0, H>(tid, j, ltok, lds, Wf, Wh, Bb, nq, xr);
  const uv8 s1r = layer_core<1, H>(tid, j, ltok, lds, Wf, Wh, Bb, nq, xr);
  const uv8 s2r = layer_core<2, H>(tid, j, ltok, lds, Wf, Wh, Bb, nq, xr);
  const uv8 s3r = layer_core<3, H>(tid, j, ltok, lds, Wf, Wh, Bb, nq, xr);

  const float r = 1.0f / (sqrtf(fmaxf(nq, 0.f)) * 0.0625f + 1e-8f);
  float* pf = (float*)lds;    // overlays Dbuf/slot0/slot1 (dead)
  const int jj = j - NWARM;

  // pass A: [r | x*r (64)]
  if (j >= NWARM) {
    if (H == 0) pf[jj*PSTR] = r;
    #pragma unroll
    for (int ii = 0; ii < 16; ++ii) {
      float xa, xb; unpack2(xr[16*H + ii], xa, xb);
      pf[jj*PSTR + 1 + 32*H + 2*ii]     = xa * r;
      pf[jj*PSTR + 1 + 32*H + 2*ii + 1] = xb * r;
    }
  }
  __syncthreads();
  if (tid < 65) {
    float s = 0.f;
    for (int k = 0; k < TOUT; ++k) s += pf[k*PSTR + tid];
    part[blk*193 + tid] = s;
  }
  __syncthreads();
  // pass B: [s0*r | s1*r]
  if (j >= NWARM) {
    #pragma unroll
    for (int m = 0; m < 8; ++m) {
      float a, b;
      unpack2(s0r[m], a, b);
      pf[jj*PSTR + 16*H + 2*m] = a * r; pf[jj*PSTR + 16*H + 2*m + 1] = b * r;
      unpack2(s1r[m], a, b);
      pf[jj*PSTR + 32 + 16*H + 2*m] = a * r; pf[jj*PSTR + 32 + 16*H + 2*m + 1] = b * r;
    }
  }
  __syncthreads();
  if (tid < 64) {
    float s = 0.f;
    for (int k = 0; k < TOUT; ++k) s += pf[k*PSTR + tid];
    part[blk*193 + 65 + tid] = s;
  }
  __syncthreads();
  // pass C: [s2*r | s3*r]
  if (j >= NWARM) {
    #pragma unroll
    for (int m = 0; m < 8; ++m) {
      float a, b;
      unpack2(s2r[m], a, b);
      pf[jj*PSTR + 16*H + 2*m] = a * r; pf[jj*PSTR + 16*H + 2*m + 1] = b * r;
      unpack2(s3r[m], a, b);
      pf[jj*PSTR + 32 + 16*H + 2*m] = a * r; pf[jj*PSTR + 32 + 16*H + 2*m + 1] = b * r;
    }
  }
  __syncthreads();
  if (tid < 64) {
    float s = 0.f;
    for (int k = 0; k < TOUT; ++k) s += pf[k*PSTR + tid];
    part[blk*193 + 129 + tid] = s;
  }
}

// ---------------------------------------------------------------------------
// Main kernel: wave-uniform half dispatch (threads 0-191 = half0 = waves 0-2).
// Both paths execute identical barrier sequences.
// ---------------------------------------------------------------------------
__global__ __launch_bounds__(2 * NHALF, 3) void ssm_main(
    const float* __restrict__ x, const float* __restrict__ Wf,
    const uint* __restrict__ Wh, const float* __restrict__ Bb,
    float* __restrict__ part)
{
  extern __shared__ uint lds[];
  if (threadIdx.x < NHALF) main_body<0>(x, Wf, Wh, Bb, part, lds);
  else                     main_body<1>(x, Wf, Wh, Bb, part, lds);
}

// ---------------------------------------------------------------------------
// Final: reduce partials, reconstruct 256-dim mean, classifier MLP.
// ---------------------------------------------------------------------------
__global__ __launch_bounds__(256) void ssm_final(
    const float* __restrict__ part,
    const float* __restrict__ in_w, const float* __restrict__ in_b,
    const float* __restrict__ Cw, const float* __restrict__ Cb,
    const float* __restrict__ fsc,
    const float* __restrict__ w1, const float* __restrict__ b1,
    const float* __restrict__ w2, const float* __restrict__ b2,
    float* __restrict__ out)
{
  const int b = blockIdx.x, t = threadIdx.x;
  __shared__ float red[193];
  __shared__ float meanv[DM];
  __shared__ float h1[DM];
  if (t < 193) {
    float s = 0.f;
    for (int k = 0; k < 64; ++k) s += part[(b*64 + k)*193 + t];
    red[t] = s;
  }
  __syncthreads();
  {
    const float rho = red[0];
    float m = in_b[t] * rho;
    #pragma unroll 4
    for (int i = 0; i < 64; ++i) m = fmaf(in_w[t*64 + i], red[1 + i], m);
    for (int l = 0; l < NL; ++l) {
      #pragma unroll 4
      for (int n = 0; n < 32; ++n)
        m = fmaf(Cw[(l*DM + t)*NS + n], red[65 + l*32 + n], m);
      m = fmaf(Cb[l*DM + t], rho, m);
    }
    meanv[t] = fsc[t] * m * (1.0f / (float)S_);
  }
  __syncthreads();
  {
    float z = b1[t];
    for (int e = 0; e < DM; ++e) z = fmaf(w1[t*DM + e], meanv[e], z);
    h1[t] = z / (1.0f + expf(-z));
  }
  __syncthreads();
  if (t < 10) {
    float lg = b2[t];
    for (int e = 0; e < DM; ++e) lg = fmaf(w2[t*DM + e], h1[e], lg);
    out[b*10 + t] = lg;
  }
}

// ---------------------------------------------------------------------------
extern "C" void kernel_launch(void* const* d_in, const int* in_sizes, int n_in,
                              void* d_out, int out_size, void* d_ws, size_t ws_size,
                              hipStream_t stream)
{
  const float* x    = (const float*)d_in[0];
  const float* in_w = (const float*)d_in[1];
  const float* in_b = (const float*)d_in[2];
  const float* logA = (const float*)d_in[3];
  const float* Bw   = (const float*)d_in[4];
  const float* Bb   = (const float*)d_in[5];
  const float* Cw   = (const float*)d_in[6];
  const float* Cb   = (const float*)d_in[7];
  const float* nsc  = (const float*)d_in[8];
  const float* fsc  = (const float*)d_in[9];
  const float* w1   = (const float*)d_in[10];
  const float* b1   = (const float*)d_in[11];
  const float* w2   = (const float*)d_in[12];
  const float* b2   = (const float*)d_in[13];
  float* out = (float*)d_out;
  float* wsf  = (float*)d_ws;
  uint*  Wh   = (uint*)(wsf + WS_WH);
  float* part = wsf + WS_PART;
  (void)in_sizes; (void)n_in; (void)out_size; (void)ws_size;

  ssm_prep<<<(PRE_N + 255) / 256, 256, 0, stream>>>(in_w, in_b, logA, Bw, Cw, Cb, nsc, wsf);
  ssm_pack<<<(WH_N + 255) / 256, 256, 0, stream>>>(wsf, Wh);
  ssm_main<<<NBLK, 2 * NHALF, LDSN * sizeof(uint), stream>>>(x, wsf, Wh, Bb, part);
  ssm_final<<<B_, 256, 0, stream>>>(part, in_w, in_b, Cw, Cb, fsc, w1, b1, w2, b2, out);
}

// Round 10
// 368.125 us; speedup vs baseline: 1.0085x; 1.0085x over previous
//
#include <hip/hip_runtime.h>
#include <hip/hip_fp16.h>
#include <math.h>

#define B_    8
#define S_    8192
#define DIN   64
#define DM    256
#define NS    32
#define NL    4
#define PIPE  192            // pipeline tokens per block (64 warm + 128 out)
#define TOUT  128
#define NWARM 64
#define HIST  16             // scan window; a^17 <= 0.35^17 ~ 7e-9
#define NBLK  (B_ * S_ / TOUT)   // 512
#define NTHR  768            // 4 lanes per token position

// ---- fp32 precomputed-weight offsets (Wf) ----
#define OFF_G   0
#define OFF_GX  4096
#define OFF_G0  4160
#define OFF_WY  4224
#define OFF_WU  12416
#define OFF_P   20608
#define OFF_R   26752
#define OFF_CY  36992
#define OFF_CU  37120
#define OFF_TX  37248
#define OFF_TV  37504
#define OFF_CT  37824
#define OFF_CC  37828
#define OFF_AV  37832
#define PRE_N   37960

// ---- packed-fp16 weight offsets (Wh, u32 units) ----
#define HOFF_G   0
#define HOFF_GX  2048
#define HOFF_WY  2080
#define HOFF_WU  6176
#define HOFF_P   10272
#define HOFF_R   13344
#define HOFF_TX  18464
#define HOFF_TV  18592
#define WH_N     18752

#define WS_WH    40960
#define WS_PART  65536

// ---- LDS: 5 buffers of [192][17] u32: Dbuf | s0 | s1 | s2 | s3(D3) ----
#define SSTR   17
#define BUFW   3264          // 192*17
#define LDSN   16320         // 5*3264 u32 = 65,280 B (<= 64 KiB dynamic cap)
#define PSTR   67            // reduce scratch stride (floats)

typedef _Float16 h2_t __attribute__((ext_vector_type(2)));
typedef uint uv4  __attribute__((ext_vector_type(4)));    // own s quarter
typedef uint uv8  __attribute__((ext_vector_type(8)));    // own x quarter
typedef uint uv32 __attribute__((ext_vector_type(32)));   // full x

__device__ __forceinline__ float h2f(ushort u) { return __half2float(__ushort_as_half(u)); }
__device__ __forceinline__ ushort f2h(float f) { return __half_as_ushort(__float2half(f)); }
__device__ __forceinline__ void unpack2(uint w, float& a, float& b) {
  a = h2f((ushort)(w & 0xffffu)); b = h2f((ushort)(w >> 16));
}
__device__ __forceinline__ uint pack2(float a, float b) {
  return (uint)f2h(a) | ((uint)f2h(b) << 16);
}
__device__ __forceinline__ float fdot2h(uint w, uint v, float c) {
  return __builtin_amdgcn_fdot2(__builtin_bit_cast(h2_t, w),
                                __builtin_bit_cast(h2_t, v), c, false);
}
__device__ __forceinline__ float quad_sum(float v) {
  v += __shfl_xor(v, 1, 64);
  v += __shfl_xor(v, 2, 64);
  return v;
}

// acc[8] += own n-quarter of W.x   (W pairs over c, n-fast 32/row)
__device__ __forceinline__ void mv64q(const uint* __restrict__ Wp, int q,
                                      uv32 xr, float acc[8]) {
  const uint* Wq = Wp + 8 * q;
  #pragma unroll 4
  for (int c2 = 0; c2 < 32; ++c2) {
    const uint xp = xr[c2];
    const uint* W0 = Wq + c2 * 32;
    #pragma unroll
    for (int k = 0; k < 8; ++k) acc[k] = fdot2h(W0[k], xp, acc[k]);
  }
}
// acc[8] += own n-quarter of M.s   (s = full packed LDS row)
__device__ __forceinline__ void mv32q(const uint* __restrict__ Mp, int q,
                                      const uint* __restrict__ srow, float acc[8]) {
  const uint* Mq = Mp + 8 * q;
  #pragma unroll 4
  for (int m2 = 0; m2 < 16; ++m2) {
    const uint sv = srow[m2];
    const uint* M0 = Mq + m2 * 32;
    #pragma unroll
    for (int k = 0; k < 8; ++k) acc[k] = fdot2h(M0[k], sv, acc[k]);
  }
}
// own quarter of tv . s (srow = full LDS row)
__device__ __forceinline__ float tvq(const uint* __restrict__ vp, int q,
                                     const uint* __restrict__ srow, float c) {
  #pragma unroll
  for (int m = 0; m < 4; ++m) c = fdot2h(vp[4*q + m], srow[4*q + m], c);
  return c;
}
__device__ __forceinline__ float dotq8(const float acc[8], uv4 s) {
  float t = 0.f;
  #pragma unroll
  for (int m = 0; m < 4; ++m) {
    float a, b; unpack2(s[m], a, b);
    t = fmaf(acc[2*m], a, t); t = fmaf(acc[2*m+1], b, t);
  }
  return t;
}

// ---------------------------------------------------------------------------
// Prep: fused fp32 matrices (identical to rounds 6-9, verified).
// ---------------------------------------------------------------------------
__global__ void ssm_prep(const float* __restrict__ in_w, const float* __restrict__ in_b,
                         const float* __restrict__ logA,
                         const float* __restrict__ Bw, const float* __restrict__ Cw,
                         const float* __restrict__ Cb, const float* __restrict__ nsc,
                         float* __restrict__ Wf)
{
  const int t = blockIdx.x * 256 + threadIdx.x;
  if (t >= PRE_N) return;
  const int pm6[6]  = {1,2,2,3,3,3}, pl6[6] = {0,0,1,0,1,2};
  const int rm10[10] = {0,1,1,2,2,2,3,3,3,3}, rl10[10] = {0,0,1,0,1,2,0,1,2,3};
  float s = 0.f;
  if (t < OFF_GX) {
    const int i = t >> 6, jj = t & 63;
    for (int d = 0; d < DM; ++d) s = fmaf(in_w[d*64 + i], in_w[d*64 + jj], s);
  } else if (t < OFF_G0) {
    const int i = t - OFF_GX;
    for (int d = 0; d < DM; ++d) s = fmaf(in_w[d*64 + i], in_b[d], s);
  } else if (t < OFF_WY) {
    if (t == OFF_G0) { for (int d = 0; d < DM; ++d) s = fmaf(in_b[d], in_b[d], s); }
  } else if (t < OFF_WU) {
    const int r = t - OFF_WY, l = r >> 11, qq = r & 2047, c = qq >> 5, n = qq & 31;
    for (int d = 0; d < DM; ++d)
      s = fmaf(Bw[(l*NS + n)*DM + d] * nsc[l*DM + d], in_w[d*64 + c], s);
  } else if (t < OFF_P) {
    const int r = t - OFF_WU, l = r >> 11, qq = r & 2047, c = qq >> 5, n = qq & 31;
    for (int d = 0; d < DM; ++d)
      s = fmaf(Cw[(l*DM + d)*NS + n], in_w[d*64 + c], s);
  } else if (t < OFF_R) {
    const int r = t - OFF_P, pi = r >> 10, qq = r & 1023, np = qq >> 5, n = qq & 31;
    const int m = pm6[pi], lp = pl6[pi];
    for (int d = 0; d < DM; ++d)
      s = fmaf(Bw[(m*NS + n)*DM + d] * nsc[m*DM + d], Cw[(lp*DM + d)*NS + np], s);
  } else if (t < OFF_CY) {
    const int r = t - OFF_R, ri = r >> 10, qq = r & 1023, np = qq >> 5, n = qq & 31;
    const int m = rm10[ri], lp = rl10[ri];
    for (int d = 0; d < DM; ++d)
      s = fmaf(Cw[(m*DM + d)*NS + n], Cw[(lp*DM + d)*NS + np], s);
  } else if (t < OFF_CU) {
    const int r = t - OFF_CY, l = r >> 5, n = r & 31;
    for (int d = 0; d < DM; ++d) {
      float bs = in_b[d];
      for (int lp = 0; lp < l; ++lp) bs += Cb[lp*DM + d];
      s = fmaf(Bw[(l*NS + n)*DM + d] * nsc[l*DM + d], bs, s);
    }
  } else if (t < OFF_TX) {
    const int r = t - OFF_CU, l = r >> 5, n = r & 31;
    for (int d = 0; d < DM; ++d) {
      float bs = in_b[d];
      for (int lp = 0; lp < l; ++lp) bs += Cb[lp*DM + d];
      s = fmaf(Cw[(l*DM + d)*NS + n], bs, s);
    }
  } else if (t < OFF_TV) {
    const int r = t - OFF_TX, l = r >> 6, i = r & 63;
    for (int d = 0; d < DM; ++d) s = fmaf(Cb[l*DM + d], in_w[d*64 + i], s);
  } else if (t < OFF_CT) {
    const int r = t - OFF_TV, vi = r >> 5, np = r & 31;
    const int m = rm10[vi], lp = rl10[vi];
    for (int d = 0; d < DM; ++d)
      s = fmaf(Cb[m*DM + d], Cw[(lp*DM + d)*NS + np], s);
  } else if (t < OFF_CC) {
    const int l = t - OFF_CT;
    for (int d = 0; d < DM; ++d) {
      float bs = in_b[d];
      for (int lp = 0; lp < l; ++lp) bs += Cb[lp*DM + d];
      s = fmaf(Cb[l*DM + d], bs, s);
    }
  } else if (t < OFF_AV) {
    const int l = t - OFF_CC;
    for (int d = 0; d < DM; ++d) s = fmaf(Cb[l*DM + d], Cb[l*DM + d], s);
  } else {
    s = 1.0f / (1.0f + expf(-logA[t - OFF_AV]));
  }
  Wf[t] = s;
}

// ---------------------------------------------------------------------------
// Pack: fp32 fused matrices -> fp16 pairs (identical to rounds 7-9, verified).
// ---------------------------------------------------------------------------
__global__ void ssm_pack(const float* __restrict__ Wf, uint* __restrict__ Wh)
{
  const int t = blockIdx.x * 256 + threadIdx.x;
  if (t >= WH_N) return;
  float a, b;
  if (t < HOFF_GX) {
    const int c2 = t >> 6, i = t & 63;
    a = Wf[OFF_G + (2*c2)*64 + i]; b = Wf[OFF_G + (2*c2+1)*64 + i];
  } else if (t < HOFF_WY) {
    const int c2 = t - HOFF_GX;
    a = Wf[OFF_GX + 2*c2]; b = Wf[OFF_GX + 2*c2 + 1];
  } else if (t < HOFF_WU) {
    const int r = t - HOFF_WY, l = r >> 10, qq = r & 1023, c2 = qq >> 5, n = qq & 31;
    a = Wf[OFF_WY + l*2048 + (2*c2)*32 + n]; b = Wf[OFF_WY + l*2048 + (2*c2+1)*32 + n];
  } else if (t < HOFF_P) {
    const int r = t - HOFF_WU, l = r >> 10, qq = r & 1023, c2 = qq >> 5, n = qq & 31;
    a = Wf[OFF_WU + l*2048 + (2*c2)*32 + n]; b = Wf[OFF_WU + l*2048 + (2*c2+1)*32 + n];
  } else if (t < HOFF_R) {
    const int r = t - HOFF_P, pi = r >> 9, qq = r & 511, m2 = qq >> 5, n = qq & 31;
    a = Wf[OFF_P + pi*1024 + (2*m2)*32 + n]; b = Wf[OFF_P + pi*1024 + (2*m2+1)*32 + n];
  } else if (t < HOFF_TX) {
    const int r = t - HOFF_R, ri = r >> 9, qq = r & 511, m2 = qq >> 5, n = qq & 31;
    a = Wf[OFF_R + ri*1024 + (2*m2)*32 + n]; b = Wf[OFF_R + ri*1024 + (2*m2+1)*32 + n];
  } else if (t < HOFF_TV) {
    const int r = t - HOFF_TX, l = r >> 5, c2 = r & 31;
    a = Wf[OFF_TX + l*64 + 2*c2]; b = Wf[OFF_TX + l*64 + 2*c2 + 1];
  } else {
    const int r = t - HOFF_TV, vi = r >> 4, m2 = r & 15;
    a = Wf[OFF_TV + vi*32 + 2*m2]; b = Wf[OFF_TV + vi*32 + 2*m2 + 1];
  }
  Wh[t] = pack2(a, b);
}

// ---------------------------------------------------------------------------
// Per-layer core (L compile-time; q runtime but only in ADDRESSES).
// Returns own s-quarter (uv4, SSA). nq combined via intra-quad shfl.
// ---------------------------------------------------------------------------
template<int L>
__device__ __forceinline__ uv4 layer_core(
    const int tid, const int j, const int q, const int ltok, uint* lds,
    const float* __restrict__ Wf, const uint* __restrict__ Wh,
    const float* __restrict__ Bb, float& nq, uv32 xr, uv8 xq)
{
  constexpr int RB = L * (L + 1) / 2;
  constexpr int PB = (L == 1) ? 0 : (L == 2) ? 1 : 3;
  uint* Dbuf  = (L < 3) ? lds : (lds + 4 * BUFW);
  uint* slotL = lds + (L + 1) * BUFW;
  const float inv = 1.0f / (sqrtf(fmaxf(nq, 0.f)) * 0.0625f + 1e-8f);

  // ---- D quarter = valid ? inv*y + Bb : 0 ----
  {
    float acc[8];
    #pragma unroll
    for (int k = 0; k < 8; ++k) acc[k] = Wf[OFF_CY + L*32 + 8*q + k];
    mv64q(Wh + HOFF_WY + L*1024, q, xr, acc);
    if constexpr (L > 0) mv32q(Wh + HOFF_P + (PB+0)*512, q, lds + 1*BUFW + j*SSTR, acc);
    if constexpr (L > 1) mv32q(Wh + HOFF_P + (PB+1)*512, q, lds + 2*BUFW + j*SSTR, acc);
    if constexpr (L > 2) mv32q(Wh + HOFF_P + (PB+2)*512, q, lds + 3*BUFW + j*SSTR, acc);
    uint* drow = Dbuf + j*SSTR + 4*q;
    const bool valid = (ltok >= 0);
    #pragma unroll
    for (int m = 0; m < 4; ++m) {
      const float v0 = valid ? fmaf(inv, acc[2*m],   Bb[L*32 + 8*q + 2*m])   : 0.f;
      const float v1 = valid ? fmaf(inv, acc[2*m+1], Bb[L*32 + 8*q + 2*m+1]) : 0.f;
      drow[m] = pack2(v0, v1);
    }
  }
  __syncthreads();

  uv4 sq;
  if constexpr (L < 3) {
    // windowed scan: first 384 threads; (n = tid&31, tg = tid>>5 in [0,12))
    if (tid < 384) {
      const int n = tid & 31, tg = tid >> 5;
      const float a = Wf[OFF_AV + L*32 + n];
      const ushort* dh = (const ushort*)Dbuf;
      ushort* sh = (ushort*)slotL;
      float carry = 0.f;
      #pragma unroll
      for (int k = 0; k < HIST; ++k) {
        const int p = tg*16 - HIST + k;
        const float v = (p >= 0) ? h2f(dh[p*(2*SSTR) + n]) : 0.f;
        carry = fmaf(a, carry, v);
      }
      #pragma unroll
      for (int k = 0; k < 16; ++k) {
        const int p = tg*16 + k;
        carry = fmaf(a, carry, h2f(dh[p*(2*SSTR) + n]));
        sh[p*(2*SSTR) + n] = f2h(carry);
      }
    }
    __syncthreads();
    #pragma unroll
    for (int m = 0; m < 4; ++m) sq[m] = slotL[j*SSTR + 4*q + m];
  } else {
    // layer 3: Horner FIR over slot3 rows (own quarter)
    float a3[8];
    #pragma unroll
    for (int k = 0; k < 8; ++k) a3[k] = Wf[OFF_AV + 96 + 8*q + k];
    float s3f[8];
    #pragma unroll
    for (int k = 0; k < 8; ++k) s3f[k] = 0.f;
    if (j >= NWARM) {
      #pragma unroll 1
      for (int lag = HIST; lag >= 0; --lag) {
        const uint* row = slotL + (j - lag)*SSTR + 4*q;
        #pragma unroll
        for (int m = 0; m < 4; ++m) {
          float v0, v1; unpack2(row[m], v0, v1);
          s3f[2*m]   = fmaf(a3[2*m],   s3f[2*m],   v0);
          s3f[2*m+1] = fmaf(a3[2*m+1], s3f[2*m+1], v1);
        }
      }
    }
    __syncthreads();   // all FIR reads of D3 done
    {
      uint* srow = slotL + j*SSTR + 4*q;
      #pragma unroll
      for (int m = 0; m < 4; ++m) { sq[m] = pack2(s3f[2*m], s3f[2*m+1]); srow[m] = sq[m]; }
    }
    __syncthreads();   // s3 published
  }

  // ---- nq update: quarter-partials, intra-quad butterfly ----
  {
    float acc2[8];
    #pragma unroll
    for (int k = 0; k < 8; ++k) acc2[k] = Wf[OFF_CU + L*32 + 8*q + k];
    mv64q(Wh + HOFF_WU + L*1024, q, xr, acc2);
    float tl = 0.f;
    #pragma unroll
    for (int m = 0; m < 8; ++m)
      tl = fdot2h(Wh[HOFF_TX + L*32 + 8*q + m], xq[m], tl);
    if constexpr (L > 0) { const uint* sr = lds + 1*BUFW + j*SSTR;
      mv32q(Wh + HOFF_R + (RB+0)*512, q, sr, acc2);
      tl = tvq(Wh + HOFF_TV + (RB+0)*16, q, sr, tl); }
    if constexpr (L > 1) { const uint* sr = lds + 2*BUFW + j*SSTR;
      mv32q(Wh + HOFF_R + (RB+1)*512, q, sr, acc2);
      tl = tvq(Wh + HOFF_TV + (RB+1)*16, q, sr, tl); }
    if constexpr (L > 2) { const uint* sr = lds + 3*BUFW + j*SSTR;
      mv32q(Wh + HOFF_R + (RB+2)*512, q, sr, acc2);
      tl = tvq(Wh + HOFF_TV + (RB+2)*16, q, sr, tl); }
    const float us = dotq8(acc2, sq);
    float acc3[8];
    #pragma unroll
    for (int k = 0; k < 8; ++k) acc3[k] = 0.f;
    const uint* sself = slotL + j*SSTR;
    mv32q(Wh + HOFF_R + (RB+L)*512, q, sself, acc3);
    const float rss = dotq8(acc3, sq);
    const float qs = tvq(Wh + HOFF_TV + (RB+L)*16, q, sself, 0.f);
    nq += quad_sum(2.f*(us + tl) + rss + 2.f*qs)
          + 2.f*Wf[OFF_CT + L] + Wf[OFF_CC + L];
  }
  return sq;
}

// ---------------------------------------------------------------------------
// Main kernel: 768 threads = 192 positions x 4 quad lanes.
// ---------------------------------------------------------------------------
__global__ __launch_bounds__(NTHR, 3) void ssm_main(
    const float* __restrict__ x, const float* __restrict__ Wf,
    const uint* __restrict__ Wh, const float* __restrict__ Bb,
    float* __restrict__ part)
{
  extern __shared__ uint lds[];
  const int tid = threadIdx.x;
  const int j = tid >> 2, q = tid & 3;
  const int blk = blockIdx.x;
  const int bb = blk >> 6;
  const int s0base = (blk & 63) * TOUT;
  const int ltok = s0base - NWARM + j;

  // full x -> regs (quad lanes share addresses; TA dedupes) + own quarter
  uv32 xr; uv8 xq;
  if (ltok >= 0) {
    const float4* xg4 = (const float4*)(x + ((size_t)bb * S_ + (size_t)ltok) * DIN);
    #pragma unroll
    for (int c4 = 0; c4 < 16; ++c4) {
      const float4 v = xg4[c4];
      xr[2*c4] = pack2(v.x, v.y); xr[2*c4+1] = pack2(v.z, v.w);
    }
    const float4* xo4 = (const float4*)(x + ((size_t)bb * S_ + (size_t)ltok) * DIN + 16*q);
    #pragma unroll
    for (int m = 0; m < 4; ++m) {
      const float4 v = xo4[m];
      xq[2*m] = pack2(v.x, v.y); xq[2*m+1] = pack2(v.z, v.w);
    }
  } else {
    #pragma unroll
    for (int m = 0; m < 32; ++m) xr[m] = 0u;
    #pragma unroll
    for (int m = 0; m < 8; ++m) xq[m] = 0u;
  }

  // nq0 = g0 + 2 gx.x + x^T G x  (quarter partials + quad butterfly)
  float nq;
  {
    float a2[16];
    #pragma unroll
    for (int i = 0; i < 16; ++i) a2[i] = 0.f;
    #pragma unroll 4
    for (int c2 = 0; c2 < 32; ++c2) {
      const uint xp = xr[c2];
      const uint* G0 = Wh + HOFF_G + c2*64 + 16*q;
      #pragma unroll
      for (int i = 0; i < 16; ++i) a2[i] = fdot2h(G0[i], xp, a2[i]);
    }
    float hd = 0.f;
    #pragma unroll
    for (int m = 0; m < 8; ++m) {
      float xa, xb; unpack2(xq[m], xa, xb);
      hd = fmaf(xa, a2[2*m], hd); hd = fmaf(xb, a2[2*m+1], hd);
    }
    float gx = 0.f;
    #pragma unroll
    for (int m = 0; m < 8; ++m)
      gx = fdot2h(Wh[HOFF_GX + 8*q + m], xq[m], gx);
    nq = quad_sum(hd + 2.f*gx) + Wf[OFF_G0];
  }

  const uv4 s0q = layer_core<0>(tid, j, q, ltok, lds, Wf, Wh, Bb, nq, xr, xq);
  const uv4 s1q = layer_core<1>(tid, j, q, ltok, lds, Wf, Wh, Bb, nq, xr, xq);
  const uv4 s2q = layer_core<2>(tid, j, q, ltok, lds, Wf, Wh, Bb, nq, xr, xq);
  const uv4 s3q = layer_core<3>(tid, j, q, ltok, lds, Wf, Wh, Bb, nq, xr, xq);

  const float r = 1.0f / (sqrtf(fmaxf(nq, 0.f)) * 0.0625f + 1e-8f);
  __syncthreads();   // all slot reads done; LDS becomes reduce scratch

  float* pf = (float*)lds;
  const int jj = j - NWARM;

  // pass A: [r | x*r (64)] — thread writes its own 16 x entries
  if (j >= NWARM) {
    if (q == 0) pf[jj*PSTR] = r;
    #pragma unroll
    for (int m = 0; m < 8; ++m) {
      float xa, xb; unpack2(xq[m], xa, xb);
      pf[jj*PSTR + 1 + 16*q + 2*m]     = xa * r;
      pf[jj*PSTR + 1 + 16*q + 2*m + 1] = xb * r;
    }
  }
  __syncthreads();
  if (tid < 65) {
    float s = 0.f;
    for (int k = 0; k < TOUT; ++k) s += pf[k*PSTR + tid];
    part[blk*193 + tid] = s;
  }
  __syncthreads();
  // pass B: [s0*r | s1*r]
  if (j >= NWARM) {
    #pragma unroll
    for (int m = 0; m < 4; ++m) {
      float a, b;
      unpack2(s0q[m], a, b);
      pf[jj*PSTR + 8*q + 2*m] = a * r;      pf[jj*PSTR + 8*q + 2*m + 1] = b * r;
      unpack2(s1q[m], a, b);
      pf[jj*PSTR + 32 + 8*q + 2*m] = a * r; pf[jj*PSTR + 32 + 8*q + 2*m + 1] = b * r;
    }
  }
  __syncthreads();
  if (tid < 64) {
    float s = 0.f;
    for (int k = 0; k < TOUT; ++k) s += pf[k*PSTR + tid];
    part[blk*193 + 65 + tid] = s;
  }
  __syncthreads();
  // pass C: [s2*r | s3*r]
  if (j >= NWARM) {
    #pragma unroll
    for (int m = 0; m < 4; ++m) {
      float a, b;
      unpack2(s2q[m], a, b);
      pf[jj*PSTR + 8*q + 2*m] = a * r;      pf[jj*PSTR + 8*q + 2*m + 1] = b * r;
      unpack2(s3q[m], a, b);
      pf[jj*PSTR + 32 + 8*q + 2*m] = a * r; pf[jj*PSTR + 32 + 8*q + 2*m + 1] = b * r;
    }
  }
  __syncthreads();
  if (tid < 64) {
    float s = 0.f;
    for (int k = 0; k < TOUT; ++k) s += pf[k*PSTR + tid];
    part[blk*193 + 129 + tid] = s;
  }
}

// ---------------------------------------------------------------------------
// Final: reduce partials, reconstruct 256-dim mean, classifier MLP.
// ---------------------------------------------------------------------------
__global__ __launch_bounds__(256) void ssm_final(
    const float* __restrict__ part,
    const float* __restrict__ in_w, const float* __restrict__ in_b,
    const float* __restrict__ Cw, const float* __restrict__ Cb,
    const float* __restrict__ fsc,
    const float* __restrict__ w1, const float* __restrict__ b1,
    const float* __restrict__ w2, const float* __restrict__ b2,
    float* __restrict__ out)
{
  const int b = blockIdx.x, t = threadIdx.x;
  __shared__ float red[193];
  __shared__ float meanv[DM];
  __shared__ float h1[DM];
  if (t < 193) {
    float s = 0.f;
    for (int k = 0; k < 64; ++k) s += part[(b*64 + k)*193 + t];
    red[t] = s;
  }
  __syncthreads();
  {
    const float rho = red[0];
    float m = in_b[t] * rho;
    #pragma unroll 4
    for (int i = 0; i < 64; ++i) m = fmaf(in_w[t*64 + i], red[1 + i], m);
    for (int l = 0; l < NL; ++l) {
      #pragma unroll 4
      for (int n = 0; n < 32; ++n)
        m = fmaf(Cw[(l*DM + t)*NS + n], red[65 + l*32 + n], m);
      m = fmaf(Cb[l*DM + t], rho, m);
    }
    meanv[t] = fsc[t] * m * (1.0f / (float)S_);
  }
  __syncthreads();
  {
    float z = b1[t];
    for (int e = 0; e < DM; ++e) z = fmaf(w1[t*DM + e], meanv[e], z);
    h1[t] = z / (1.0f + expf(-z));
  }
  __syncthreads();
  if (t < 10) {
    float lg = b2[t];
    for (int e = 0; e < DM; ++e) lg = fmaf(w2[t*DM + e], h1[e], lg);
    out[b*10 + t] = lg;
  }
}

// ---------------------------------------------------------------------------
extern "C" void kernel_launch(void* const* d_in, const int* in_sizes, int n_in,
                              void* d_out, int out_size, void* d_ws, size_t ws_size,
                              hipStream_t stream)
{
  const float* x    = (const float*)d_in[0];
  const float* in_w = (const float*)d_in[1];
  const float* in_b = (const float*)d_in[2];
  const float* logA = (const float*)d_in[3];
  const float* Bw   = (const float*)d_in[4];
  const float* Bb   = (const float*)d_in[5];
  const float* Cw   = (const float*)d_in[6];
  const float* Cb   = (const float*)d_in[7];
  const float* nsc  = (const float*)d_in[8];
  const float* fsc  = (const float*)d_in[9];
  const float* w1   = (const float*)d_in[10];
  const float* b1   = (const float*)d_in[11];
  const float* w2   = (const float*)d_in[12];
  const float* b2   = (const float*)d_in[13];
  float* out = (float*)d_out;
  float* wsf  = (float*)d_ws;
  uint*  Wh   = (uint*)(wsf + WS_WH);
  float* part = wsf + WS_PART;
  (void)in_sizes; (void)n_in; (void)out_size; (void)ws_size;

  ssm_prep<<<(PRE_N + 255) / 256, 256, 0, stream>>>(in_w, in_b, logA, Bw, Cw, Cb, nsc, wsf);
  ssm_pack<<<(WH_N + 255) / 256, 256, 0, stream>>>(wsf, Wh);
  ssm_main<<<NBLK, NTHR, LDSN * sizeof(uint), stream>>>(x, wsf, Wh, Bb, part);
  ssm_final<<<B_, 256, 0, stream>>>(part, in_w, in_b, Cw, Cb, fsc, w1, b1, w2, b2, out);
}

// Round 11
// 138.056 us; speedup vs baseline: 2.6893x; 2.6665x over previous
//
#include <hip/hip_runtime.h>
#include <hip/hip_fp16.h>
#include <math.h>

#define B_    8
#define S_    8192
#define DIN   64
#define DM    256
#define NS    32
#define NL    4
#define TOUT  64
#define NWARM 64
#define PIPE  128            // 64 warm + 64 out
#define HIST  16             // scan window; a^17 ~ 7e-9
#define NBLK  1024           // B_*S_/TOUT
#define NTHR  256            // 4 waves; 2 Mtiles (32 tokens) per wave

// ---- fp32 precomputed-weight offsets (Wf) ----
#define OFF_G   0
#define OFF_GX  4096
#define OFF_G0  4160
#define OFF_WY  4224
#define OFF_WU  12416
#define OFF_P   20608
#define OFF_R   26752
#define OFF_CY  36992
#define OFF_CU  37120
#define OFF_TX  37248
#define OFF_TV  37504
#define OFF_CT  37824
#define OFF_CC  37828
#define OFF_AV  37832
#define PRE_N   37960

// ---- frag buffer (u32 units). 72 frag-units of 256 u32 + TX/TV tails ----
#define TXOFF  18432         // 4*32 u32
#define TVOFF  18560         // 10*16 u32
#define WS_FRAG 40960        // float offset of Fr in ws
#define WS_PART 65536        // float offset of part[1024][193]

// ---- LDS u32 layout ----
#define LX    0              // x [128][34]
#define LD    4352           // D [128][17]
#define LS0   6528           // slots l: LS0 + l*2176, [128][17] each
#define LNQ   15232          // float[128]
#define LTL   15360          // float[128]
#define LDSN  15488          // 61,952 B

typedef _Float16 h2_t  __attribute__((ext_vector_type(2)));
typedef _Float16 f16x8 __attribute__((ext_vector_type(8)));
typedef float    f32x4 __attribute__((ext_vector_type(4)));
typedef uint     uv4   __attribute__((ext_vector_type(4)));

__device__ __forceinline__ float h2f(ushort u) { return __half2float(__ushort_as_half(u)); }
__device__ __forceinline__ ushort f2h(float f) { return __half_as_ushort(__float2half(f)); }
__device__ __forceinline__ uint pack2(float a, float b) {
  return (uint)f2h(a) | ((uint)f2h(b) << 16);
}
__device__ __forceinline__ float fdot2h(uint w, uint v, float c) {
  return __builtin_amdgcn_fdot2(__builtin_bit_cast(h2_t, w),
                                __builtin_bit_cast(h2_t, v), c, false);
}
__device__ __forceinline__ f32x4 MF(uv4 a, uv4 b, f32x4 c) {
  return __builtin_amdgcn_mfma_f32_16x16x32_f16(
      __builtin_bit_cast(f16x8, a), __builtin_bit_cast(f16x8, b), c, 0, 0, 0);
}
__device__ __forceinline__ uv4 ldB(const uint* __restrict__ Fr, int unit, int lane) {
  return ((const uv4*)Fr)[unit * 64 + lane];
}

// ---------------------------------------------------------------------------
// Prep: fused fp32 matrices (identical to rounds 6-10, verified).
// ---------------------------------------------------------------------------
__global__ void ssm_prep(const float* __restrict__ in_w, const float* __restrict__ in_b,
                         const float* __restrict__ logA,
                         const float* __restrict__ Bw, const float* __restrict__ Cw,
                         const float* __restrict__ Cb, const float* __restrict__ nsc,
                         float* __restrict__ Wf)
{
  const int t = blockIdx.x * 256 + threadIdx.x;
  if (t >= PRE_N) return;
  const int pm6[6]  = {1,2,2,3,3,3}, pl6[6] = {0,0,1,0,1,2};
  const int rm10[10] = {0,1,1,2,2,2,3,3,3,3}, rl10[10] = {0,0,1,0,1,2,0,1,2,3};
  float s = 0.f;
  if (t < OFF_GX) {
    const int i = t >> 6, jj = t & 63;
    for (int d = 0; d < DM; ++d) s = fmaf(in_w[d*64 + i], in_w[d*64 + jj], s);
  } else if (t < OFF_G0) {
    const int i = t - OFF_GX;
    for (int d = 0; d < DM; ++d) s = fmaf(in_w[d*64 + i], in_b[d], s);
  } else if (t < OFF_WY) {
    if (t == OFF_G0) { for (int d = 0; d < DM; ++d) s = fmaf(in_b[d], in_b[d], s); }
  } else if (t < OFF_WU) {
    const int r = t - OFF_WY, l = r >> 11, qq = r & 2047, c = qq >> 5, n = qq & 31;
    for (int d = 0; d < DM; ++d)
      s = fmaf(Bw[(l*NS + n)*DM + d] * nsc[l*DM + d], in_w[d*64 + c], s);
  } else if (t < OFF_P) {
    const int r = t - OFF_WU, l = r >> 11, qq = r & 2047, c = qq >> 5, n = qq & 31;
    for (int d = 0; d < DM; ++d)
      s = fmaf(Cw[(l*DM + d)*NS + n], in_w[d*64 + c], s);
  } else if (t < OFF_R) {
    const int r = t - OFF_P, pi = r >> 10, qq = r & 1023, np = qq >> 5, n = qq & 31;
    const int m = pm6[pi], lp = pl6[pi];
    for (int d = 0; d < DM; ++d)
      s = fmaf(Bw[(m*NS + n)*DM + d] * nsc[m*DM + d], Cw[(lp*DM + d)*NS + np], s);
  } else if (t < OFF_CY) {
    const int r = t - OFF_R, ri = r >> 10, qq = r & 1023, np = qq >> 5, n = qq & 31;
    const int m = rm10[ri], lp = rl10[ri];
    for (int d = 0; d < DM; ++d)
      s = fmaf(Cw[(m*DM + d)*NS + n], Cw[(lp*DM + d)*NS + np], s);
  } else if (t < OFF_CU) {
    const int r = t - OFF_CY, l = r >> 5, n = r & 31;
    for (int d = 0; d < DM; ++d) {
      float bs = in_b[d];
      for (int lp = 0; lp < l; ++lp) bs += Cb[lp*DM + d];
      s = fmaf(Bw[(l*NS + n)*DM + d] * nsc[l*DM + d], bs, s);
    }
  } else if (t < OFF_TX) {
    const int r = t - OFF_CU, l = r >> 5, n = r & 31;
    for (int d = 0; d < DM; ++d) {
      float bs = in_b[d];
      for (int lp = 0; lp < l; ++lp) bs += Cb[lp*DM + d];
      s = fmaf(Cw[(l*DM + d)*NS + n], bs, s);
    }
  } else if (t < OFF_TV) {
    const int r = t - OFF_TX, l = r >> 6, i = r & 63;
    for (int d = 0; d < DM; ++d) s = fmaf(Cb[l*DM + d], in_w[d*64 + i], s);
  } else if (t < OFF_CT) {
    const int r = t - OFF_TV, vi = r >> 5, np = r & 31;
    const int m = rm10[vi], lp = rl10[vi];
    for (int d = 0; d < DM; ++d)
      s = fmaf(Cb[m*DM + d], Cw[(lp*DM + d)*NS + np], s);
  } else if (t < OFF_CC) {
    const int l = t - OFF_CT;
    for (int d = 0; d < DM; ++d) {
      float bs = in_b[d];
      for (int lp = 0; lp < l; ++lp) bs += Cb[lp*DM + d];
      s = fmaf(Cb[l*DM + d], bs, s);
    }
  } else if (t < OFF_AV) {
    const int l = t - OFF_CC;
    for (int d = 0; d < DM; ++d) s = fmaf(Cb[l*DM + d], Cb[l*DM + d], s);
  } else {
    s = 1.0f / (1.0f + expf(-logA[t - OFF_AV]));
  }
  Wf[t] = s;
}

// ---------------------------------------------------------------------------
// Pack B-fragments for mfma_f32_16x16x32_f16 from Wf.
// Frag unit = 256 u32 = 64 lanes x 4 u32 (8 fp16, k-pairs).
// B[k][n]: lane = 16*(k_octet) + n_lo; u32 c holds k = oct*8 + 2c, 2c+1.
// Units: G: k*4+nt (8) | WY: 8+l*4+k*2+nt (16) | WU: 24+... (16) |
//        P: 40+pi*2+nt (12) | R: 52+ri*2+nt (20; self scaled 0.5).
// ---------------------------------------------------------------------------
__global__ void ssm_packfrag(const float* __restrict__ Wf, uint* __restrict__ Fr)
{
  const int u = blockIdx.x, t = threadIdx.x;
  if (u < 72) {
    const int lane = t >> 2, c = t & 3;
    const int li = lane & 15, lb = lane >> 4;
    float a, b;
    if (u < 8) {
      const int k = u >> 2, nt = u & 3;
      const int n = nt*16 + li, kk = k*32 + lb*8 + 2*c;
      a = Wf[OFF_G + kk*64 + n]; b = Wf[OFF_G + (kk+1)*64 + n];
    } else if (u < 24) {
      const int r = u - 8, l = r >> 2, k = (r >> 1) & 1, nt = r & 1;
      const int n = nt*16 + li, kk = k*32 + lb*8 + 2*c;
      a = Wf[OFF_WY + l*2048 + kk*32 + n]; b = Wf[OFF_WY + l*2048 + (kk+1)*32 + n];
    } else if (u < 40) {
      const int r = u - 24, l = r >> 2, k = (r >> 1) & 1, nt = r & 1;
      const int n = nt*16 + li, kk = k*32 + lb*8 + 2*c;
      a = Wf[OFF_WU + l*2048 + kk*32 + n]; b = Wf[OFF_WU + l*2048 + (kk+1)*32 + n];
    } else if (u < 52) {
      const int r = u - 40, pi = r >> 1, nt = r & 1;
      const int n = nt*16 + li, kk = lb*8 + 2*c;
      a = Wf[OFF_P + pi*1024 + kk*32 + n]; b = Wf[OFF_P + pi*1024 + (kk+1)*32 + n];
    } else {
      const int r = u - 52, ri = r >> 1, nt = r & 1;
      const int n = nt*16 + li, kk = lb*8 + 2*c;
      const float sc = (ri == 0 || ri == 2 || ri == 5 || ri == 9) ? 0.5f : 1.f;
      a = sc * Wf[OFF_R + ri*1024 + kk*32 + n];
      b = sc * Wf[OFF_R + ri*1024 + (kk+1)*32 + n];
    }
    Fr[u*256 + lane*4 + c] = pack2(a, b);
  } else if (u == 72) {
    if (t < 128) { const int l = t >> 5, c2 = t & 31;
      Fr[TXOFF + t] = pack2(Wf[OFF_TX + l*64 + 2*c2], Wf[OFF_TX + l*64 + 2*c2 + 1]); }
  } else {
    if (t < 160) { const int vi = t >> 4, m2 = t & 15;
      Fr[TVOFF + t] = pack2(Wf[OFF_TV + vi*32 + 2*m2], Wf[OFF_TV + vi*32 + 2*m2 + 1]); }
  }
}

// ---------------------------------------------------------------------------
// Per-layer body (L compile-time): Y MFMA -> D write -> scan -> U MFMA -> nq.
// ---------------------------------------------------------------------------
template<int L>
__device__ __forceinline__ void layer_mfma(
    const int tid, const int lane, const int wid, const int s0base,
    uint* lds, const float* __restrict__ Wf, const uint* __restrict__ Fr,
    const float* __restrict__ Bb,
    const uv4 (&xf)[2][2], uv4 (&sf0)[2], uv4 (&sf1)[2], uv4 (&sf2)[2], uv4 (&sf3)[2])
{
  constexpr int RB = L * (L + 1) / 2;
  constexpr int PB = (L == 1) ? 0 : (L == 2) ? 1 : 3;
  float*  ldsF = (float*)lds;
  ushort* ldsH = (ushort*)lds;
  const int li = lane & 15, q4 = (lane >> 4) & 3;

  // per-lane constants for this layer
  float cy[2], bb[2], cu[2], tvs[2];
  #pragma unroll
  for (int nt = 0; nt < 2; ++nt) {
    const int nn = nt*16 + li;
    cy[nt]  = Wf[OFF_CY + L*32 + nn];
    bb[nt]  = Bb[L*32 + nn];
    cu[nt]  = Wf[OFF_CU + L*32 + nn];
    tvs[nt] = Wf[OFF_TV + (RB + L)*32 + nn];
  }
  // inv(nq) per owned token row
  float invv[2][4];
  #pragma unroll
  for (int m = 0; m < 2; ++m)
    #pragma unroll
    for (int r = 0; r < 4; ++r) {
      const int tk = wid*32 + m*16 + q4*4 + r;
      const float nqv = ldsF[LNQ + tk];
      invv[m][r] = 1.0f / (sqrtf(fmaxf(nqv, 0.f)) * 0.0625f + 1e-8f);
    }

  // ---- Y phase + D write ----
  #pragma unroll
  for (int nt = 0; nt < 2; ++nt) {
    const uv4 by0 = ldB(Fr, 8 + L*4 + 0*2 + nt, lane);
    const uv4 by1 = ldB(Fr, 8 + L*4 + 1*2 + nt, lane);
    uv4 bp0, bp1, bp2;
    if constexpr (L > 0) bp0 = ldB(Fr, 40 + (PB + 0)*2 + nt, lane);
    if constexpr (L > 1) bp1 = ldB(Fr, 40 + (PB + 1)*2 + nt, lane);
    if constexpr (L > 2) bp2 = ldB(Fr, 40 + (PB + 2)*2 + nt, lane);
    #pragma unroll
    for (int m = 0; m < 2; ++m) {
      f32x4 c = {cy[nt], cy[nt], cy[nt], cy[nt]};
      c = MF(xf[m][0], by0, c);
      c = MF(xf[m][1], by1, c);
      if constexpr (L > 0) c = MF(sf0[m], bp0, c);
      if constexpr (L > 1) c = MF(sf1[m], bp1, c);
      if constexpr (L > 2) c = MF(sf2[m], bp2, c);
      #pragma unroll
      for (int r = 0; r < 4; ++r) {
        const int tk = wid*32 + m*16 + q4*4 + r;
        const bool valid = (s0base > 0) || (tk >= NWARM);
        const float v = valid ? fmaf(invv[m][r], c[r], bb[nt]) : 0.f;
        ldsH[LD*2 + tk*34 + nt*16 + li] = f2h(v);
      }
    }
  }
  __syncthreads();

  // ---- scan (all 256 threads: n = tid&31, group = tid>>5 over 16 tokens) ----
  {
    const int n = tid & 31, g = tid >> 5;
    const float a = Wf[OFF_AV + L*32 + n];
    float carry = 0.f;
    #pragma unroll
    for (int k = 0; k < HIST; ++k) {
      const int p = g*16 - HIST + k;
      const float v = (p >= 0) ? h2f(ldsH[LD*2 + p*34 + n]) : 0.f;
      carry = fmaf(a, carry, v);
    }
    #pragma unroll
    for (int k = 0; k < 16; ++k) {
      const int p = g*16 + k;
      carry = fmaf(a, carry, h2f(ldsH[LD*2 + p*34 + n]));
      ldsH[(LS0 + L*2176)*2 + p*34 + n] = f2h(carry);
    }
  }
  // ---- tl per token (reads x + slots lp<L; writes LTL) ----
  if (tid < PIPE) {
    float tl = Wf[OFF_CT + L];
    const uint* xr = lds + LX + tid*34;
    #pragma unroll 8
    for (int c2 = 0; c2 < 32; ++c2) tl = fdot2h(Fr[TXOFF + L*32 + c2], xr[c2], tl);
    if constexpr (L > 0) { const uint* sr = lds + LS0 + 0*2176 + tid*17;
      #pragma unroll
      for (int m2 = 0; m2 < 16; ++m2) tl = fdot2h(Fr[TVOFF + (RB+0)*16 + m2], sr[m2], tl); }
    if constexpr (L > 1) { const uint* sr = lds + LS0 + 1*2176 + tid*17;
      #pragma unroll
      for (int m2 = 0; m2 < 16; ++m2) tl = fdot2h(Fr[TVOFF + (RB+1)*16 + m2], sr[m2], tl); }
    if constexpr (L > 2) { const uint* sr = lds + LS0 + 2*2176 + tid*17;
      #pragma unroll
      for (int m2 = 0; m2 < 16; ++m2) tl = fdot2h(Fr[TVOFF + (RB+2)*16 + m2], sr[m2], tl); }
    ldsF[LTL + tid] = tl;
  }
  __syncthreads();

  // ---- load S_L A-frags ----
  uv4 sA[2];
  #pragma unroll
  for (int m = 0; m < 2; ++m) {
    const uint* p = lds + LS0 + L*2176 + (wid*32 + m*16 + li)*17 + q4*4;
    uv4 v; v[0] = p[0]; v[1] = p[1]; v[2] = p[2]; v[3] = p[3];
    sA[m] = v;
  }
  if constexpr (L == 0)      { sf0[0] = sA[0]; sf0[1] = sA[1]; }
  else if constexpr (L == 1) { sf1[0] = sA[0]; sf1[1] = sA[1]; }
  else if constexpr (L == 2) { sf2[0] = sA[0]; sf2[1] = sA[1]; }
  else                       { sf3[0] = sA[0]; sf3[1] = sA[1]; }

  // ---- U/ACC phase + w row-dot ----
  float wv[2][4] = {{0.f,0.f,0.f,0.f},{0.f,0.f,0.f,0.f}};
  #pragma unroll
  for (int nt = 0; nt < 2; ++nt) {
    const uv4 bu0 = ldB(Fr, 24 + L*4 + 0*2 + nt, lane);
    const uv4 bu1 = ldB(Fr, 24 + L*4 + 1*2 + nt, lane);
    uv4 br0, br1, br2;
    if constexpr (L > 0) br0 = ldB(Fr, 52 + (RB + 0)*2 + nt, lane);
    if constexpr (L > 1) br1 = ldB(Fr, 52 + (RB + 1)*2 + nt, lane);
    if constexpr (L > 2) br2 = ldB(Fr, 52 + (RB + 2)*2 + nt, lane);
    const uv4 brS = ldB(Fr, 52 + (RB + L)*2 + nt, lane);   // 0.5*R_self
    #pragma unroll
    for (int m = 0; m < 2; ++m) {
      f32x4 c = {0.f, 0.f, 0.f, 0.f};
      c = MF(xf[m][0], bu0, c);
      c = MF(xf[m][1], bu1, c);
      if constexpr (L > 0) c = MF(sf0[m], br0, c);
      if constexpr (L > 1) c = MF(sf1[m], br1, c);
      if constexpr (L > 2) c = MF(sf2[m], br2, c);
      c = MF(sA[m], brS, c);
      #pragma unroll
      for (int r = 0; r < 4; ++r) {
        const int tk = wid*32 + m*16 + q4*4 + r;
        const float sv = h2f(ldsH[(LS0 + L*2176)*2 + tk*34 + nt*16 + li]);
        wv[m][r] = fmaf(c[r] + cu[nt] + tvs[nt], sv, wv[m][r]);
      }
    }
  }
  #pragma unroll
  for (int m = 0; m < 2; ++m)
    #pragma unroll
    for (int r = 0; r < 4; ++r) {
      float v = wv[m][r];
      v += __shfl_xor(v, 1, 64); v += __shfl_xor(v, 2, 64);
      v += __shfl_xor(v, 4, 64); v += __shfl_xor(v, 8, 64);
      wv[m][r] = v;
    }
  if (li == 0) {
    #pragma unroll
    for (int m = 0; m < 2; ++m)
      #pragma unroll
      for (int r = 0; r < 4; ++r) {
        const int tk = wid*32 + m*16 + q4*4 + r;
        ldsF[LNQ + tk] += 2.f * (wv[m][r] + ldsF[LTL + tk]);
      }
  }
  __syncthreads();
}

// ---------------------------------------------------------------------------
// Main kernel (MFMA engine).
// ---------------------------------------------------------------------------
__global__ __launch_bounds__(NTHR, 2) void ssm_main(
    const float* __restrict__ x, const float* __restrict__ Wf,
    const uint* __restrict__ Fr, const float* __restrict__ Bb,
    float* __restrict__ part)
{
  extern __shared__ uint lds[];
  float*  ldsF = (float*)lds;
  ushort* ldsH = (ushort*)lds;
  const int tid = threadIdx.x;
  const int lane = tid & 63, wid = tid >> 6;
  const int li = lane & 15, q4 = (lane >> 4) & 3;
  const int blk = blockIdx.x;
  const int bb = blk >> 7;                 // 128 blocks per sequence
  const int s0base = (blk & 127) * TOUT;

  // ---- stage x -> fp16 LDS rows [128][34] ----
  {
    const float4* xg4 = (const float4*)(x + (size_t)bb * S_ * DIN);
    #pragma unroll
    for (int k = 0; k < 8; ++k) {
      const int idx = k * NTHR + tid;
      const int tok = idx >> 4, c4 = idx & 15;
      const int lt = s0base - NWARM + tok;
      float4 v = make_float4(0.f, 0.f, 0.f, 0.f);
      if (lt >= 0) v = xg4[lt * 16 + c4];
      lds[LX + tok*34 + 2*c4]     = pack2(v.x, v.y);
      lds[LX + tok*34 + 2*c4 + 1] = pack2(v.z, v.w);
    }
  }
  __syncthreads();

  // ---- X A-frags (resident) ----
  uv4 xf[2][2];
  #pragma unroll
  for (int m = 0; m < 2; ++m)
    #pragma unroll
    for (int k = 0; k < 2; ++k) {
      const uint* p = lds + LX + (wid*32 + m*16 + li)*34 + k*16 + q4*4;
      uv4 v; v[0] = p[0]; v[1] = p[1]; v[2] = p[2]; v[3] = p[3];
      xf[m][k] = v;
    }

  // ---- nq0 = g0 + 2 gx.x + x^T G x  via XG MFMA + row-dot ----
  {
    float val[2][4] = {{0.f,0.f,0.f,0.f},{0.f,0.f,0.f,0.f}};
    #pragma unroll
    for (int nt = 0; nt < 4; ++nt) {
      const float gxv = 2.f * Wf[OFF_GX + nt*16 + li];
      const uv4 bg0 = ldB(Fr, 0*4 + nt, lane);
      const uv4 bg1 = ldB(Fr, 1*4 + nt, lane);
      #pragma unroll
      for (int m = 0; m < 2; ++m) {
        f32x4 c = {gxv, gxv, gxv, gxv};
        c = MF(xf[m][0], bg0, c);
        c = MF(xf[m][1], bg1, c);
        #pragma unroll
        for (int r = 0; r < 4; ++r) {
          const int tk = wid*32 + m*16 + q4*4 + r;
          const float xv = h2f(ldsH[LX*2 + tk*34*2/2*1 + tk*0 + tk*34 + nt*16 + li]); // = ldsH[tk*68/2...]
          val[m][r] = fmaf(c[r], xv, val[m][r]);
        }
      }
    }
    const float g0 = Wf[OFF_G0];
    #pragma unroll
    for (int m = 0; m < 2; ++m)
      #pragma unroll
      for (int r = 0; r < 4; ++r) {
        float v = val[m][r];
        v += __shfl_xor(v, 1, 64); v += __shfl_xor(v, 2, 64);
        v += __shfl_xor(v, 4, 64); v += __shfl_xor(v, 8, 64);
        if (li == 0) ldsF[LNQ + wid*32 + m*16 + q4*4 + r] = g0 + v;
      }
  }
  __syncthreads();

  // ---- layers ----
  uv4 sf0[2], sf1[2], sf2[2], sf3[2];
  layer_mfma<0>(tid, lane, wid, s0base, lds, Wf, Fr, Bb, xf, sf0, sf1, sf2, sf3);
  layer_mfma<1>(tid, lane, wid, s0base, lds, Wf, Fr, Bb, xf, sf0, sf1, sf2, sf3);
  layer_mfma<2>(tid, lane, wid, s0base, lds, Wf, Fr, Bb, xf, sf0, sf1, sf2, sf3);
  layer_mfma<3>(tid, lane, wid, s0base, lds, Wf, Fr, Bb, xf, sf0, sf1, sf2, sf3);

  // ---- final r + block partial sums ----
  float rr = 0.f;
  if (tid >= NWARM && tid < PIPE)
    rr = 1.0f / (sqrtf(fmaxf(ldsF[LNQ + tid], 0.f)) * 0.0625f + 1e-8f);
  const int jj = tid - NWARM;
  float* pfA = (float*)(lds + LD);   // 64 x 33
  float* pfB = (float*)(lds + LX);   // 64 x 65

  // pass A1: [r | x0..31 * r]  (x re-read fp32 from global)
  if (tid >= NWARM && tid < PIPE) {
    pfA[jj*33] = rr;
    const float4* xr4 = (const float4*)(x + ((size_t)bb * S_ + (size_t)(s0base + jj)) * DIN);
    #pragma unroll
    for (int c4 = 0; c4 < 8; ++c4) {
      const float4 v = xr4[c4];
      pfA[jj*33 + 1 + 4*c4] = v.x * rr; pfA[jj*33 + 2 + 4*c4] = v.y * rr;
      pfA[jj*33 + 3 + 4*c4] = v.z * rr; pfA[jj*33 + 4 + 4*c4] = v.w * rr;
    }
  }
  __syncthreads();
  if (tid < 33) { float s = 0.f;
    for (int k = 0; k < TOUT; ++k) s += pfA[k*33 + tid];
    part[blk*193 + tid] = s; }
  __syncthreads();
  // pass A2: x32..63 * r
  if (tid >= NWARM && tid < PIPE) {
    const float4* xr4 = (const float4*)(x + ((size_t)bb * S_ + (size_t)(s0base + jj)) * DIN);
    #pragma unroll
    for (int c4 = 8; c4 < 16; ++c4) {
      const float4 v = xr4[c4];
      const int o = 4*c4 - 32;
      pfA[jj*33 + o]     = v.x * rr; pfA[jj*33 + o + 1] = v.y * rr;
      pfA[jj*33 + o + 2] = v.z * rr; pfA[jj*33 + o + 3] = v.w * rr;
    }
  }
  __syncthreads();
  if (tid < 32) { float s = 0.f;
    for (int k = 0; k < TOUT; ++k) s += pfA[k*33 + tid];
    part[blk*193 + 33 + tid] = s; }
  __syncthreads();
  // pass B: [s0 | s1] * r
  if (tid >= NWARM && tid < PIPE) {
    #pragma unroll
    for (int m2 = 0; m2 < 16; ++m2) {
      const uint w0 = lds[LS0 + 0*2176 + tid*17 + m2];
      const uint w1 = lds[LS0 + 1*2176 + tid*17 + m2];
      pfB[jj*65 + 2*m2]          = h2f((ushort)(w0 & 0xffffu)) * rr;
      pfB[jj*65 + 2*m2 + 1]      = h2f((ushort)(w0 >> 16)) * rr;
      pfB[jj*65 + 32 + 2*m2]     = h2f((ushort)(w1 & 0xffffu)) * rr;
      pfB[jj*65 + 32 + 2*m2 + 1] = h2f((ushort)(w1 >> 16)) * rr;
    }
  }
  __syncthreads();
  if (tid < 64) { float s = 0.f;
    for (int k = 0; k < TOUT; ++k) s += pfB[k*65 + tid];
    part[blk*193 + 65 + tid] = s; }
  __syncthreads();
  // pass C: [s2 | s3] * r
  if (tid >= NWARM && tid < PIPE) {
    #pragma unroll
    for (int m2 = 0; m2 < 16; ++m2) {
      const uint w2v = lds[LS0 + 2*2176 + tid*17 + m2];
      const uint w3v = lds[LS0 + 3*2176 + tid*17 + m2];
      pfB[jj*65 + 2*m2]          = h2f((ushort)(w2v & 0xffffu)) * rr;
      pfB[jj*65 + 2*m2 + 1]      = h2f((ushort)(w2v >> 16)) * rr;
      pfB[jj*65 + 32 + 2*m2]     = h2f((ushort)(w3v & 0xffffu)) * rr;
      pfB[jj*65 + 32 + 2*m2 + 1] = h2f((ushort)(w3v >> 16)) * rr;
    }
  }
  __syncthreads();
  if (tid < 64) { float s = 0.f;
    for (int k = 0; k < TOUT; ++k) s += pfB[k*65 + tid];
    part[blk*193 + 129 + tid] = s; }
}

// ---------------------------------------------------------------------------
// Final: reduce partials, reconstruct 256-dim mean, classifier MLP.
// ---------------------------------------------------------------------------
__global__ __launch_bounds__(256) void ssm_final(
    const float* __restrict__ part,
    const float* __restrict__ in_w, const float* __restrict__ in_b,
    const float* __restrict__ Cw, const float* __restrict__ Cb,
    const float* __restrict__ fsc,
    const float* __restrict__ w1, const float* __restrict__ b1,
    const float* __restrict__ w2, const float* __restrict__ b2,
    float* __restrict__ out)
{
  const int b = blockIdx.x, t = threadIdx.x;
  __shared__ float red[193];
  __shared__ float meanv[DM];
  __shared__ float h1[DM];
  if (t < 193) {
    float s = 0.f;
    for (int k = 0; k < 128; ++k) s += part[(b*128 + k)*193 + t];
    red[t] = s;
  }
  __syncthreads();
  {
    const float rho = red[0];
    float m = in_b[t] * rho;
    #pragma unroll 4
    for (int i = 0; i < 64; ++i) m = fmaf(in_w[t*64 + i], red[1 + i], m);
    for (int l = 0; l < NL; ++l) {
      #pragma unroll 4
      for (int n = 0; n < 32; ++n)
        m = fmaf(Cw[(l*DM + t)*NS + n], red[65 + l*32 + n], m);
      m = fmaf(Cb[l*DM + t], rho, m);
    }
    meanv[t] = fsc[t] * m * (1.0f / (float)S_);
  }
  __syncthreads();
  {
    float z = b1[t];
    for (int e = 0; e < DM; ++e) z = fmaf(w1[t*DM + e], meanv[e], z);
    h1[t] = z / (1.0f + expf(-z));
  }
  __syncthreads();
  if (t < 10) {
    float lg = b2[t];
    for (int e = 0; e < DM; ++e) lg = fmaf(w2[t*DM + e], h1[e], lg);
    out[b*10 + t] = lg;
  }
}

// ---------------------------------------------------------------------------
extern "C" void kernel_launch(void* const* d_in, const int* in_sizes, int n_in,
                              void* d_out, int out_size, void* d_ws, size_t ws_size,
                              hipStream_t stream)
{
  const float* x    = (const float*)d_in[0];
  const float* in_w = (const float*)d_in[1];
  const float* in_b = (const float*)d_in[2];
  const float* logA = (const float*)d_in[3];
  const float* Bw   = (const float*)d_in[4];
  const float* Bb   = (const float*)d_in[5];
  const float* Cw   = (const float*)d_in[6];
  const float* Cb   = (const float*)d_in[7];
  const float* nsc  = (const float*)d_in[8];
  const float* fsc  = (const float*)d_in[9];
  const float* w1   = (const float*)d_in[10];
  const float* b1   = (const float*)d_in[11];
  const float* w2   = (const float*)d_in[12];
  const float* b2   = (const float*)d_in[13];
  float* out  = (float*)d_out;
  float* wsf  = (float*)d_ws;
  uint*  Fr   = (uint*)(wsf + WS_FRAG);
  float* part = wsf + WS_PART;
  (void)in_sizes; (void)n_in; (void)out_size; (void)ws_size;

  ssm_prep<<<(PRE_N + 255) / 256, 256, 0, stream>>>(in_w, in_b, logA, Bw, Cw, Cb, nsc, wsf);
  ssm_packfrag<<<74, 256, 0, stream>>>(wsf, Fr);
  ssm_main<<<NBLK, NTHR, LDSN * sizeof(uint), stream>>>(x, wsf, Fr, Bb, part);
  ssm_final<<<B_, 256, 0, stream>>>(part, in_w, in_b, Cw, Cb, fsc, w1, b1, w2, b2, out);
}

// Round 12
// 121.863 us; speedup vs baseline: 3.0466x; 1.1329x over previous
//
#include <hip/hip_runtime.h>
#include <hip/hip_fp16.h>
#include <math.h>

#define B_    8
#define S_    8192
#define DIN   64
#define DM    256
#define NS    32
#define NL    4
#define TOUT  64
#define NWARM 64
#define PIPE  128            // 64 warm + 64 out
#define HIST  16             // scan window; a^17 ~ 7e-9
#define NBLK  1024           // B_*S_/TOUT
#define NTHR  256            // 4 waves; 2 Mtiles (32 tokens) per wave

// ---- fp32 precomputed-weight offsets (Wf) ----
#define OFF_G   0
#define OFF_GX  4096
#define OFF_G0  4160
#define OFF_WY  4224
#define OFF_WU  12416
#define OFF_P   20608
#define OFF_R   26752
#define OFF_CY  36992
#define OFF_CU  37120
#define OFF_TX  37248
#define OFF_TV  37504
#define OFF_CT  37824
#define OFF_CC  37828
#define OFF_AV  37832
#define PRE_N   37960

// ---- frag buffer (u32 units). 72 frag-units of 256 u32 + TX/TV tails ----
#define TXOFF  18432         // 4*32 u32
#define TVOFF  18560         // 10*16 u32
#define WS_FRAG 40960        // float offset of Fr in ws
#define WS_PART 65536        // float offset of part[1024][193]

// ---- LDS u32 layout (D merged into s-slots; 53,248 B -> 3 blocks/CU) ----
#define LX    0              // x [128][34]
#define LS0   4352           // slot L: LS0 + L*2176, [128][17] each
#define LNQ   13056          // float[128]
#define LTL   13184          // float[128]
#define LDSN  13312          // 53,248 B

typedef _Float16 h2_t  __attribute__((ext_vector_type(2)));
typedef _Float16 f16x8 __attribute__((ext_vector_type(8)));
typedef float    f32x4 __attribute__((ext_vector_type(4)));
typedef uint     uv4   __attribute__((ext_vector_type(4)));

__device__ __forceinline__ float h2f(ushort u) { return __half2float(__ushort_as_half(u)); }
__device__ __forceinline__ ushort f2h(float f) { return __half_as_ushort(__float2half(f)); }
__device__ __forceinline__ uint pack2(float a, float b) {
  return (uint)f2h(a) | ((uint)f2h(b) << 16);
}
__device__ __forceinline__ float fdot2h(uint w, uint v, float c) {
  return __builtin_amdgcn_fdot2(__builtin_bit_cast(h2_t, w),
                                __builtin_bit_cast(h2_t, v), c, false);
}
__device__ __forceinline__ f32x4 MF(uv4 a, uv4 b, f32x4 c) {
  return __builtin_amdgcn_mfma_f32_16x16x32_f16(
      __builtin_bit_cast(f16x8, a), __builtin_bit_cast(f16x8, b), c, 0, 0, 0);
}
__device__ __forceinline__ uv4 ldB(const uint* __restrict__ Fr, int unit, int lane) {
  return ((const uv4*)Fr)[unit * 64 + lane];
}

// ---------------------------------------------------------------------------
// Prep: fused fp32 matrices. 4 lanes per output (64 d-iters each) +
// intra-quad shfl reduce -> 4x parallelism vs rounds 6-11.
// ---------------------------------------------------------------------------
__global__ void ssm_prep(const float* __restrict__ in_w, const float* __restrict__ in_b,
                         const float* __restrict__ logA,
                         const float* __restrict__ Bw, const float* __restrict__ Cw,
                         const float* __restrict__ Cb, const float* __restrict__ nsc,
                         float* __restrict__ Wf)
{
  const int gid = blockIdx.x * 256 + threadIdx.x;
  const int t = gid >> 2, piece = gid & 3;
  if (t >= PRE_N) return;
  const int d0 = piece * 64, d1 = d0 + 64;
  const int pm6[6]  = {1,2,2,3,3,3}, pl6[6] = {0,0,1,0,1,2};
  const int rm10[10] = {0,1,1,2,2,2,3,3,3,3}, rl10[10] = {0,0,1,0,1,2,0,1,2,3};
  float s = 0.f;
  if (t < OFF_GX) {
    const int i = t >> 6, jj = t & 63;
    for (int d = d0; d < d1; ++d) s = fmaf(in_w[d*64 + i], in_w[d*64 + jj], s);
  } else if (t < OFF_G0) {
    const int i = t - OFF_GX;
    for (int d = d0; d < d1; ++d) s = fmaf(in_w[d*64 + i], in_b[d], s);
  } else if (t < OFF_WY) {
    if (t == OFF_G0) { for (int d = d0; d < d1; ++d) s = fmaf(in_b[d], in_b[d], s); }
  } else if (t < OFF_WU) {
    const int r = t - OFF_WY, l = r >> 11, qq = r & 2047, c = qq >> 5, n = qq & 31;
    for (int d = d0; d < d1; ++d)
      s = fmaf(Bw[(l*NS + n)*DM + d] * nsc[l*DM + d], in_w[d*64 + c], s);
  } else if (t < OFF_P) {
    const int r = t - OFF_WU, l = r >> 11, qq = r & 2047, c = qq >> 5, n = qq & 31;
    for (int d = d0; d < d1; ++d)
      s = fmaf(Cw[(l*DM + d)*NS + n], in_w[d*64 + c], s);
  } else if (t < OFF_R) {
    const int r = t - OFF_P, pi = r >> 10, qq = r & 1023, np = qq >> 5, n = qq & 31;
    const int m = pm6[pi], lp = pl6[pi];
    for (int d = d0; d < d1; ++d)
      s = fmaf(Bw[(m*NS + n)*DM + d] * nsc[m*DM + d], Cw[(lp*DM + d)*NS + np], s);
  } else if (t < OFF_CY) {
    const int r = t - OFF_R, ri = r >> 10, qq = r & 1023, np = qq >> 5, n = qq & 31;
    const int m = rm10[ri], lp = rl10[ri];
    for (int d = d0; d < d1; ++d)
      s = fmaf(Cw[(m*DM + d)*NS + n], Cw[(lp*DM + d)*NS + np], s);
  } else if (t < OFF_CU) {
    const int r = t - OFF_CY, l = r >> 5, n = r & 31;
    for (int d = d0; d < d1; ++d) {
      float bs = in_b[d];
      for (int lp = 0; lp < l; ++lp) bs += Cb[lp*DM + d];
      s = fmaf(Bw[(l*NS + n)*DM + d] * nsc[l*DM + d], bs, s);
    }
  } else if (t < OFF_TX) {
    const int r = t - OFF_CU, l = r >> 5, n = r & 31;
    for (int d = d0; d < d1; ++d) {
      float bs = in_b[d];
      for (int lp = 0; lp < l; ++lp) bs += Cb[lp*DM + d];
      s = fmaf(Cw[(l*DM + d)*NS + n], bs, s);
    }
  } else if (t < OFF_TV) {
    const int r = t - OFF_TX, l = r >> 6, i = r & 63;
    for (int d = d0; d < d1; ++d) s = fmaf(Cb[l*DM + d], in_w[d*64 + i], s);
  } else if (t < OFF_CT) {
    const int r = t - OFF_TV, vi = r >> 5, np = r & 31;
    const int m = rm10[vi], lp = rl10[vi];
    for (int d = d0; d < d1; ++d)
      s = fmaf(Cb[m*DM + d], Cw[(lp*DM + d)*NS + np], s);
  } else if (t < OFF_CC) {
    const int l = t - OFF_CT;
    for (int d = d0; d < d1; ++d) {
      float bs = in_b[d];
      for (int lp = 0; lp < l; ++lp) bs += Cb[lp*DM + d];
      s = fmaf(Cb[l*DM + d], bs, s);
    }
  } else if (t < OFF_AV) {
    const int l = t - OFF_CC;
    for (int d = d0; d < d1; ++d) s = fmaf(Cb[l*DM + d], Cb[l*DM + d], s);
  } else {
    s = (piece == 0) ? 1.0f / (1.0f + expf(-logA[t - OFF_AV])) : 0.f;
  }
  s += __shfl_xor(s, 1, 64);
  s += __shfl_xor(s, 2, 64);
  if (piece == 0) Wf[t] = s;
}

// ---------------------------------------------------------------------------
// Pack B-fragments for mfma_f32_16x16x32_f16 (identical to round 11, verified)
// ---------------------------------------------------------------------------
__global__ void ssm_packfrag(const float* __restrict__ Wf, uint* __restrict__ Fr)
{
  const int u = blockIdx.x, t = threadIdx.x;
  if (u < 72) {
    const int lane = t >> 2, c = t & 3;
    const int li = lane & 15, lb = lane >> 4;
    float a, b;
    if (u < 8) {
      const int k = u >> 2, nt = u & 3;
      const int n = nt*16 + li, kk = k*32 + lb*8 + 2*c;
      a = Wf[OFF_G + kk*64 + n]; b = Wf[OFF_G + (kk+1)*64 + n];
    } else if (u < 24) {
      const int r = u - 8, l = r >> 2, k = (r >> 1) & 1, nt = r & 1;
      const int n = nt*16 + li, kk = k*32 + lb*8 + 2*c;
      a = Wf[OFF_WY + l*2048 + kk*32 + n]; b = Wf[OFF_WY + l*2048 + (kk+1)*32 + n];
    } else if (u < 40) {
      const int r = u - 24, l = r >> 2, k = (r >> 1) & 1, nt = r & 1;
      const int n = nt*16 + li, kk = k*32 + lb*8 + 2*c;
      a = Wf[OFF_WU + l*2048 + kk*32 + n]; b = Wf[OFF_WU + l*2048 + (kk+1)*32 + n];
    } else if (u < 52) {
      const int r = u - 40, pi = r >> 1, nt = r & 1;
      const int n = nt*16 + li, kk = lb*8 + 2*c;
      a = Wf[OFF_P + pi*1024 + kk*32 + n]; b = Wf[OFF_P + pi*1024 + (kk+1)*32 + n];
    } else {
      const int r = u - 52, ri = r >> 1, nt = r & 1;
      const int n = nt*16 + li, kk = lb*8 + 2*c;
      const float sc = (ri == 0 || ri == 2 || ri == 5 || ri == 9) ? 0.5f : 1.f;
      a = sc * Wf[OFF_R + ri*1024 + kk*32 + n];
      b = sc * Wf[OFF_R + ri*1024 + (kk+1)*32 + n];
    }
    Fr[u*256 + lane*4 + c] = pack2(a, b);
  } else if (u == 72) {
    if (t < 128) { const int l = t >> 5, c2 = t & 31;
      Fr[TXOFF + t] = pack2(Wf[OFF_TX + l*64 + 2*c2], Wf[OFF_TX + l*64 + 2*c2 + 1]); }
  } else {
    if (t < 160) { const int vi = t >> 4, m2 = t & 15;
      Fr[TVOFF + t] = pack2(Wf[OFF_TV + vi*32 + 2*m2], Wf[OFF_TV + vi*32 + 2*m2 + 1]); }
  }
}

// ---------------------------------------------------------------------------
// Per-layer body: Y MFMA -> D write (into slot L) -> in-place scan
// (reg-stage + barrier) -> U MFMA -> nq.
// ---------------------------------------------------------------------------
template<int L>
__device__ __forceinline__ void layer_mfma(
    const int tid, const int lane, const int wid, const int s0base,
    uint* lds, const float* __restrict__ Wf, const uint* __restrict__ Fr,
    const float* __restrict__ Bb,
    const uv4 (&xf)[2][2], uv4 (&sf0)[2], uv4 (&sf1)[2], uv4 (&sf2)[2], uv4 (&sf3)[2])
{
  constexpr int RB = L * (L + 1) / 2;
  constexpr int PB = (L == 1) ? 0 : (L == 2) ? 1 : 3;
  constexpr int SL = LS0 + L * 2176;
  float*  ldsF = (float*)lds;
  ushort* ldsH = (ushort*)lds;
  const int li = lane & 15, q4 = (lane >> 4) & 3;

  // per-lane constants for this layer
  float cy[2], bb2[2], cu[2], tvs[2];
  #pragma unroll
  for (int nt = 0; nt < 2; ++nt) {
    const int nn = nt*16 + li;
    cy[nt]  = Wf[OFF_CY + L*32 + nn];
    bb2[nt] = Bb[L*32 + nn];
    cu[nt]  = Wf[OFF_CU + L*32 + nn];
    tvs[nt] = Wf[OFF_TV + (RB + L)*32 + nn];
  }
  // inv(nq) per owned token row
  float invv[2][4];
  #pragma unroll
  for (int m = 0; m < 2; ++m)
    #pragma unroll
    for (int r = 0; r < 4; ++r) {
      const int tk = wid*32 + m*16 + q4*4 + r;
      invv[m][r] = 1.0f / (sqrtf(fmaxf(ldsF[LNQ + tk], 0.f)) * 0.0625f + 1e-8f);
    }

  // ---- Y phase + D write (into slot L) ----
  #pragma unroll
  for (int nt = 0; nt < 2; ++nt) {
    const uv4 by0 = ldB(Fr, 8 + L*4 + 0*2 + nt, lane);
    const uv4 by1 = ldB(Fr, 8 + L*4 + 1*2 + nt, lane);
    uv4 bp0, bp1, bp2;
    if constexpr (L > 0) bp0 = ldB(Fr, 40 + (PB + 0)*2 + nt, lane);
    if constexpr (L > 1) bp1 = ldB(Fr, 40 + (PB + 1)*2 + nt, lane);
    if constexpr (L > 2) bp2 = ldB(Fr, 40 + (PB + 2)*2 + nt, lane);
    #pragma unroll
    for (int m = 0; m < 2; ++m) {
      f32x4 c = {cy[nt], cy[nt], cy[nt], cy[nt]};
      c = MF(xf[m][0], by0, c);
      c = MF(xf[m][1], by1, c);
      if constexpr (L > 0) c = MF(sf0[m], bp0, c);
      if constexpr (L > 1) c = MF(sf1[m], bp1, c);
      if constexpr (L > 2) c = MF(sf2[m], bp2, c);
      #pragma unroll
      for (int r = 0; r < 4; ++r) {
        const int tk = wid*32 + m*16 + q4*4 + r;
        const bool valid = (s0base > 0) || (tk >= NWARM);
        const float v = valid ? fmaf(invv[m][r], c[r], bb2[nt]) : 0.f;
        ldsH[SL*2 + tk*34 + nt*16 + li] = f2h(v);
      }
    }
  }
  __syncthreads();   // B1: D visible

  // ---- in-place scan, stage 1: read 32 D values into regs ----
  const int n = tid & 31, g = tid >> 5;
  const float a = Wf[OFF_AV + L*32 + n];
  float dv[32];
  #pragma unroll
  for (int k = 0; k < 32; ++k) {
    const int p = g*16 - HIST + k;
    dv[k] = (p >= 0) ? h2f(ldsH[SL*2 + p*34 + n]) : 0.f;
  }
  __syncthreads();   // B2: all D reads complete before s overwrites

  // ---- stage 2: Horner chain + write s in place ----
  {
    float carry = 0.f;
    #pragma unroll
    for (int k = 0; k < 32; ++k) {
      carry = fmaf(a, carry, dv[k]);
      if (k >= HIST) ldsH[SL*2 + (g*16 + k - HIST)*34 + n] = f2h(carry);
    }
  }
  // ---- tl per token (x + slots lp<L; none touches slot L) ----
  if (tid < PIPE) {
    float tl = Wf[OFF_CT + L];
    const uint* xr = lds + LX + tid*34;
    #pragma unroll 8
    for (int c2 = 0; c2 < 32; ++c2) tl = fdot2h(Fr[TXOFF + L*32 + c2], xr[c2], tl);
    if constexpr (L > 0) { const uint* sr = lds + LS0 + 0*2176 + tid*17;
      #pragma unroll
      for (int m2 = 0; m2 < 16; ++m2) tl = fdot2h(Fr[TVOFF + (RB+0)*16 + m2], sr[m2], tl); }
    if constexpr (L > 1) { const uint* sr = lds + LS0 + 1*2176 + tid*17;
      #pragma unroll
      for (int m2 = 0; m2 < 16; ++m2) tl = fdot2h(Fr[TVOFF + (RB+1)*16 + m2], sr[m2], tl); }
    if constexpr (L > 2) { const uint* sr = lds + LS0 + 2*2176 + tid*17;
      #pragma unroll
      for (int m2 = 0; m2 < 16; ++m2) tl = fdot2h(Fr[TVOFF + (RB+2)*16 + m2], sr[m2], tl); }
    ldsF[LTL + tid] = tl;
  }
  __syncthreads();   // B3: s + tl visible

  // ---- load S_L A-frags ----
  uv4 sA[2];
  #pragma unroll
  for (int m = 0; m < 2; ++m) {
    const uint* p = lds + SL + (wid*32 + m*16 + li)*17 + q4*4;
    uv4 v; v[0] = p[0]; v[1] = p[1]; v[2] = p[2]; v[3] = p[3];
    sA[m] = v;
  }
  if constexpr (L == 0)      { sf0[0] = sA[0]; sf0[1] = sA[1]; }
  else if constexpr (L == 1) { sf1[0] = sA[0]; sf1[1] = sA[1]; }
  else if constexpr (L == 2) { sf2[0] = sA[0]; sf2[1] = sA[1]; }
  else                       { sf3[0] = sA[0]; sf3[1] = sA[1]; }

  // ---- U/ACC phase + w row-dot ----
  float wv[2][4] = {{0.f,0.f,0.f,0.f},{0.f,0.f,0.f,0.f}};
  #pragma unroll
  for (int nt = 0; nt < 2; ++nt) {
    const uv4 bu0 = ldB(Fr, 24 + L*4 + 0*2 + nt, lane);
    const uv4 bu1 = ldB(Fr, 24 + L*4 + 1*2 + nt, lane);
    uv4 br0, br1, br2;
    if constexpr (L > 0) br0 = ldB(Fr, 52 + (RB + 0)*2 + nt, lane);
    if constexpr (L > 1) br1 = ldB(Fr, 52 + (RB + 1)*2 + nt, lane);
    if constexpr (L > 2) br2 = ldB(Fr, 52 + (RB + 2)*2 + nt, lane);
    const uv4 brS = ldB(Fr, 52 + (RB + L)*2 + nt, lane);   // 0.5*R_self
    #pragma unroll
    for (int m = 0; m < 2; ++m) {
      f32x4 c = {0.f, 0.f, 0.f, 0.f};
      c = MF(xf[m][0], bu0, c);
      c = MF(xf[m][1], bu1, c);
      if constexpr (L > 0) c = MF(sf0[m], br0, c);
      if constexpr (L > 1) c = MF(sf1[m], br1, c);
      if constexpr (L > 2) c = MF(sf2[m], br2, c);
      c = MF(sA[m], brS, c);
      #pragma unroll
      for (int r = 0; r < 4; ++r) {
        const int tk = wid*32 + m*16 + q4*4 + r;
        const float sv = h2f(ldsH[SL*2 + tk*34 + nt*16 + li]);
        wv[m][r] = fmaf(c[r] + cu[nt] + tvs[nt], sv, wv[m][r]);
      }
    }
  }
  #pragma unroll
  for (int m = 0; m < 2; ++m)
    #pragma unroll
    for (int r = 0; r < 4; ++r) {
      float v = wv[m][r];
      v += __shfl_xor(v, 1, 64); v += __shfl_xor(v, 2, 64);
      v += __shfl_xor(v, 4, 64); v += __shfl_xor(v, 8, 64);
      wv[m][r] = v;
    }
  if (li == 0) {
    #pragma unroll
    for (int m = 0; m < 2; ++m)
      #pragma unroll
      for (int r = 0; r < 4; ++r) {
        const int tk = wid*32 + m*16 + q4*4 + r;
        ldsF[LNQ + tk] += 2.f * (wv[m][r] + ldsF[LTL + tk]);
      }
  }
  __syncthreads();   // B4: nq updated
}

// ---------------------------------------------------------------------------
// Main kernel (MFMA engine, 3 blocks/CU).
// ---------------------------------------------------------------------------
__global__ __launch_bounds__(NTHR, 3) void ssm_main(
    const float* __restrict__ x, const float* __restrict__ Wf,
    const uint* __restrict__ Fr, const float* __restrict__ Bb,
    float* __restrict__ part)
{
  extern __shared__ uint lds[];
  float*  ldsF = (float*)lds;
  ushort* ldsH = (ushort*)lds;
  const int tid = threadIdx.x;
  const int lane = tid & 63, wid = tid >> 6;
  const int li = lane & 15, q4 = (lane >> 4) & 3;
  const int blk = blockIdx.x;
  const int bb = blk >> 7;                 // 128 blocks per sequence
  const int s0base = (blk & 127) * TOUT;

  // ---- stage x -> fp16 LDS rows [128][34] ----
  {
    const float4* xg4 = (const float4*)(x + (size_t)bb * S_ * DIN);
    #pragma unroll
    for (int k = 0; k < 8; ++k) {
      const int idx = k * NTHR + tid;
      const int tok = idx >> 4, c4 = idx & 15;
      const int lt = s0base - NWARM + tok;
      float4 v = make_float4(0.f, 0.f, 0.f, 0.f);
      if (lt >= 0) v = xg4[lt * 16 + c4];
      lds[LX + tok*34 + 2*c4]     = pack2(v.x, v.y);
      lds[LX + tok*34 + 2*c4 + 1] = pack2(v.z, v.w);
    }
  }
  __syncthreads();

  // ---- X A-frags (resident) ----
  uv4 xf[2][2];
  #pragma unroll
  for (int m = 0; m < 2; ++m)
    #pragma unroll
    for (int k = 0; k < 2; ++k) {
      const uint* p = lds + LX + (wid*32 + m*16 + li)*34 + k*16 + q4*4;
      uv4 v; v[0] = p[0]; v[1] = p[1]; v[2] = p[2]; v[3] = p[3];
      xf[m][k] = v;
    }

  // ---- nq0 = g0 + 2 gx.x + x^T G x  via XG MFMA + row-dot ----
  {
    float val[2][4] = {{0.f,0.f,0.f,0.f},{0.f,0.f,0.f,0.f}};
    #pragma unroll
    for (int nt = 0; nt < 4; ++nt) {
      const float gxv = 2.f * Wf[OFF_GX + nt*16 + li];
      const uv4 bg0 = ldB(Fr, 0*4 + nt, lane);
      const uv4 bg1 = ldB(Fr, 1*4 + nt, lane);
      #pragma unroll
      for (int m = 0; m < 2; ++m) {
        f32x4 c = {gxv, gxv, gxv, gxv};
        c = MF(xf[m][0], bg0, c);
        c = MF(xf[m][1], bg1, c);
        #pragma unroll
        for (int r = 0; r < 4; ++r) {
          const int tk = wid*32 + m*16 + q4*4 + r;
          const float xv = h2f(ldsH[tk*68 + nt*16 + li]);
          val[m][r] = fmaf(c[r], xv, val[m][r]);
        }
      }
    }
    const float g0 = Wf[OFF_G0];
    #pragma unroll
    for (int m = 0; m < 2; ++m)
      #pragma unroll
      for (int r = 0; r < 4; ++r) {
        float v = val[m][r];
        v += __shfl_xor(v, 1, 64); v += __shfl_xor(v, 2, 64);
        v += __shfl_xor(v, 4, 64); v += __shfl_xor(v, 8, 64);
        if (li == 0) ldsF[LNQ + wid*32 + m*16 + q4*4 + r] = g0 + v;
      }
  }
  __syncthreads();

  // ---- layers ----
  uv4 sf0[2], sf1[2], sf2[2], sf3[2];
  layer_mfma<0>(tid, lane, wid, s0base, lds, Wf, Fr, Bb, xf, sf0, sf1, sf2, sf3);
  layer_mfma<1>(tid, lane, wid, s0base, lds, Wf, Fr, Bb, xf, sf0, sf1, sf2, sf3);
  layer_mfma<2>(tid, lane, wid, s0base, lds, Wf, Fr, Bb, xf, sf0, sf1, sf2, sf3);
  layer_mfma<3>(tid, lane, wid, s0base, lds, Wf, Fr, Bb, xf, sf0, sf1, sf2, sf3);

  // ---- final r + block partial sums ----
  float rr = 0.f;
  if (tid >= NWARM && tid < PIPE)
    rr = 1.0f / (sqrtf(fmaxf(ldsF[LNQ + tid], 0.f)) * 0.0625f + 1e-8f);
  const int jj = tid - NWARM;
  float* pfA = (float*)(lds + LX);   // 64 x 33  (x region dead)
  float* pfB = (float*)(lds + LX);   // 64 x 65  (4160 <= 4352)

  // pass A1: [r | x0..31 * r]  (x re-read fp32 from global)
  if (tid >= NWARM && tid < PIPE) {
    pfA[jj*33] = rr;
    const float4* xr4 = (const float4*)(x + ((size_t)bb * S_ + (size_t)(s0base + jj)) * DIN);
    #pragma unroll
    for (int c4 = 0; c4 < 8; ++c4) {
      const float4 v = xr4[c4];
      pfA[jj*33 + 1 + 4*c4] = v.x * rr; pfA[jj*33 + 2 + 4*c4] = v.y * rr;
      pfA[jj*33 + 3 + 4*c4] = v.z * rr; pfA[jj*33 + 4 + 4*c4] = v.w * rr;
    }
  }
  __syncthreads();
  if (tid < 33) { float s = 0.f;
    for (int k = 0; k < TOUT; ++k) s += pfA[k*33 + tid];
    part[blk*193 + tid] = s; }
  __syncthreads();
  // pass A2: x32..63 * r
  if (tid >= NWARM && tid < PIPE) {
    const float4* xr4 = (const float4*)(x + ((size_t)bb * S_ + (size_t)(s0base + jj)) * DIN);
    #pragma unroll
    for (int c4 = 8; c4 < 16; ++c4) {
      const float4 v = xr4[c4];
      const int o = 4*c4 - 32;
      pfA[jj*33 + o]     = v.x * rr; pfA[jj*33 + o + 1] = v.y * rr;
      pfA[jj*33 + o + 2] = v.z * rr; pfA[jj*33 + o + 3] = v.w * rr;
    }
  }
  __syncthreads();
  if (tid < 32) { float s = 0.f;
    for (int k = 0; k < TOUT; ++k) s += pfA[k*33 + tid];
    part[blk*193 + 33 + tid] = s; }
  __syncthreads();
  // pass B: [s0 | s1] * r
  if (tid >= NWARM && tid < PIPE) {
    #pragma unroll
    for (int m2 = 0; m2 < 16; ++m2) {
      const uint w0 = lds[LS0 + 0*2176 + tid*17 + m2];
      const uint w1 = lds[LS0 + 1*2176 + tid*17 + m2];
      pfB[jj*65 + 2*m2]          = h2f((ushort)(w0 & 0xffffu)) * rr;
      pfB[jj*65 + 2*m2 + 1]      = h2f((ushort)(w0 >> 16)) * rr;
      pfB[jj*65 + 32 + 2*m2]     = h2f((ushort)(w1 & 0xffffu)) * rr;
      pfB[jj*65 + 32 + 2*m2 + 1] = h2f((ushort)(w1 >> 16)) * rr;
    }
  }
  __syncthreads();
  if (tid < 64) { float s = 0.f;
    for (int k = 0; k < TOUT; ++k) s += pfB[k*65 + tid];
    part[blk*193 + 65 + tid] = s; }
  __syncthreads();
  // pass C: [s2 | s3] * r
  if (tid >= NWARM && tid < PIPE) {
    #pragma unroll
    for (int m2 = 0; m2 < 16; ++m2) {
      const uint w2v = lds[LS0 + 2*2176 + tid*17 + m2];
      const uint w3v = lds[LS0 + 3*2176 + tid*17 + m2];
      pfB[jj*65 + 2*m2]          = h2f((ushort)(w2v & 0xffffu)) * rr;
      pfB[jj*65 + 2*m2 + 1]      = h2f((ushort)(w2v >> 16)) * rr;
      pfB[jj*65 + 32 + 2*m2]     = h2f((ushort)(w3v & 0xffffu)) * rr;
      pfB[jj*65 + 32 + 2*m2 + 1] = h2f((ushort)(w3v >> 16)) * rr;
    }
  }
  __syncthreads();
  if (tid < 64) { float s = 0.f;
    for (int k = 0; k < TOUT; ++k) s += pfB[k*65 + tid];
    part[blk*193 + 129 + tid] = s; }
}

// ---------------------------------------------------------------------------
// Final: reduce partials (4-way ILP), reconstruct mean, classifier MLP.
// ---------------------------------------------------------------------------
__global__ __launch_bounds__(256) void ssm_final(
    const float* __restrict__ part,
    const float* __restrict__ in_w, const float* __restrict__ in_b,
    const float* __restrict__ Cw, const float* __restrict__ Cb,
    const float* __restrict__ fsc,
    const float* __restrict__ w1, const float* __restrict__ b1,
    const float* __restrict__ w2, const float* __restrict__ b2,
    float* __restrict__ out)
{
  const int b = blockIdx.x, t = threadIdx.x;
  __shared__ float red[193];
  __shared__ float meanv[DM];
  __shared__ float h1[DM];
  if (t < 193) {
    float a0 = 0.f, a1 = 0.f, a2 = 0.f, a3 = 0.f;
    const float* pp = part + (size_t)b * 128 * 193 + t;
    for (int k = 0; k < 128; k += 4) {
      a0 += pp[(k + 0) * 193]; a1 += pp[(k + 1) * 193];
      a2 += pp[(k + 2) * 193]; a3 += pp[(k + 3) * 193];
    }
    red[t] = (a0 + a1) + (a2 + a3);
  }
  __syncthreads();
  {
    const float rho = red[0];
    float m = in_b[t] * rho;
    #pragma unroll 4
    for (int i = 0; i < 64; ++i) m = fmaf(in_w[t*64 + i], red[1 + i], m);
    for (int l = 0; l < NL; ++l) {
      #pragma unroll 4
      for (int n = 0; n < 32; ++n)
        m = fmaf(Cw[(l*DM + t)*NS + n], red[65 + l*32 + n], m);
      m = fmaf(Cb[l*DM + t], rho, m);
    }
    meanv[t] = fsc[t] * m * (1.0f / (float)S_);
  }
  __syncthreads();
  {
    float z = b1[t];
    for (int e = 0; e < DM; ++e) z = fmaf(w1[t*DM + e], meanv[e], z);
    h1[t] = z / (1.0f + expf(-z));
  }
  __syncthreads();
  if (t < 10) {
    float lg = b2[t];
    for (int e = 0; e < DM; ++e) lg = fmaf(w2[t*DM + e], h1[e], lg);
    out[b*10 + t] = lg;
  }
}

// ---------------------------------------------------------------------------
extern "C" void kernel_launch(void* const* d_in, const int* in_sizes, int n_in,
                              void* d_out, int out_size, void* d_ws, size_t ws_size,
                              hipStream_t stream)
{
  const float* x    = (const float*)d_in[0];
  const float* in_w = (const float*)d_in[1];
  const float* in_b = (const float*)d_in[2];
  const float* logA = (const float*)d_in[3];
  const float* Bw   = (const float*)d_in[4];
  const float* Bb   = (const float*)d_in[5];
  const float* Cw   = (const float*)d_in[6];
  const float* Cb   = (const float*)d_in[7];
  const float* nsc  = (const float*)d_in[8];
  const float* fsc  = (const float*)d_in[9];
  const float* w1   = (const float*)d_in[10];
  const float* b1   = (const float*)d_in[11];
  const float* w2   = (const float*)d_in[12];
  const float* b2   = (const float*)d_in[13];
  float* out  = (float*)d_out;
  float* wsf  = (float*)d_ws;
  uint*  Fr   = (uint*)(wsf + WS_FRAG);
  float* part = wsf + WS_PART;
  (void)in_sizes; (void)n_in; (void)out_size; (void)ws_size;

  ssm_prep<<<(PRE_N * 4 + 255) / 256, 256, 0, stream>>>(in_w, in_b, logA, Bw, Cw, Cb, nsc, wsf);
  ssm_packfrag<<<74, 256, 0, stream>>>(wsf, Fr);
  ssm_main<<<NBLK, NTHR, LDSN * sizeof(uint), stream>>>(x, wsf, Fr, Bb, part);
  ssm_final<<<B_, 256, 0, stream>>>(part, in_w, in_b, Cw, Cb, fsc, w1, b1, w2, b2, out);
}

// Round 13
// 98.244 us; speedup vs baseline: 3.7791x; 1.2404x over previous
//
#include <hip/hip_runtime.h>
#include <hip/hip_fp16.h>
#include <math.h>

#define B_    8
#define S_    8192
#define DIN   64
#define DM    256
#define NS    32
#define NL    4
#define TOUT  128
#define NWARM 64
#define PIPE  192            // 64 warm + 128 out
#define HIST  16             // scan window; a^17 ~ 7e-9
#define NBLK  512            // B_*S_/TOUT -> exactly 2 blocks/CU, zero tail
#define NTHR  256            // 4 waves; 3 Mtiles (48 tokens) per wave

// ---- fp32 precomputed-weight offsets (Wf) ----
#define OFF_G   0
#define OFF_GX  4096
#define OFF_G0  4160
#define OFF_WY  4224
#define OFF_WU  12416
#define OFF_P   20608
#define OFF_R   26752
#define OFF_CY  36992
#define OFF_CU  37120
#define OFF_TX  37248
#define OFF_TV  37504
#define OFF_CT  37824
#define OFF_CC  37828
#define OFF_AV  37832
#define PRE_N   37960

// ---- frag buffer (u32 units). 72 frag-units of 256 u32 + TX/TV tails ----
#define TXOFF  18432         // 4*32 u32
#define TVOFF  18560         // 10*16 u32
#define WS_FRAG 40960        // float offset of Fr in ws
#define WS_PART 65536        // float offset of part[512][193]

// ---- LDS u32 layout: x[192][34] | slots[4][192][17] | nq | tl ----
#define LX    0
#define LS0   6528           // slot L: LS0 + L*3264
#define LNQ   19584          // float[192]
#define LTL   19776          // float[192]
#define LDSN  19968          // 79,872 B -> 2 blocks/CU

typedef _Float16 h2_t  __attribute__((ext_vector_type(2)));
typedef _Float16 f16x8 __attribute__((ext_vector_type(8)));
typedef float    f32x4 __attribute__((ext_vector_type(4)));
typedef uint     uv4   __attribute__((ext_vector_type(4)));

__device__ __forceinline__ float h2f(ushort u) { return __half2float(__ushort_as_half(u)); }
__device__ __forceinline__ ushort f2h(float f) { return __half_as_ushort(__float2half(f)); }
__device__ __forceinline__ uint pack2(float a, float b) {
  return (uint)f2h(a) | ((uint)f2h(b) << 16);
}
__device__ __forceinline__ float fdot2h(uint w, uint v, float c) {
  return __builtin_amdgcn_fdot2(__builtin_bit_cast(h2_t, w),
                                __builtin_bit_cast(h2_t, v), c, false);
}
__device__ __forceinline__ f32x4 MF(uv4 a, uv4 b, f32x4 c) {
  return __builtin_amdgcn_mfma_f32_16x16x32_f16(
      __builtin_bit_cast(f16x8, a), __builtin_bit_cast(f16x8, b), c, 0, 0, 0);
}
__device__ __forceinline__ uv4 ldB(const uint* __restrict__ Fr, int unit, int lane) {
  return ((const uv4*)Fr)[unit * 64 + lane];
}

// ---------------------------------------------------------------------------
// Prep: fused fp32 matrices + DIRECT fp16 fragment packing (packfrag fused).
// 4 lanes per output (64 d-iters each) + intra-quad shfl reduce.
// ---------------------------------------------------------------------------
__global__ void ssm_prep(const float* __restrict__ in_w, const float* __restrict__ in_b,
                         const float* __restrict__ logA,
                         const float* __restrict__ Bw, const float* __restrict__ Cw,
                         const float* __restrict__ Cb, const float* __restrict__ nsc,
                         float* __restrict__ Wf, ushort* __restrict__ FrH)
{
  const int gid = blockIdx.x * 256 + threadIdx.x;
  const int t = gid >> 2, piece = gid & 3;
  if (t >= PRE_N) return;
  const int d0 = piece * 64, d1 = d0 + 64;
  const int pm6[6]  = {1,2,2,3,3,3}, pl6[6] = {0,0,1,0,1,2};
  const int rm10[10] = {0,1,1,2,2,2,3,3,3,3}, rl10[10] = {0,0,1,0,1,2,0,1,2,3};
  float s = 0.f;
  if (t < OFF_GX) {
    const int i = t >> 6, jj = t & 63;
    for (int d = d0; d < d1; ++d) s = fmaf(in_w[d*64 + i], in_w[d*64 + jj], s);
  } else if (t < OFF_G0) {
    const int i = t - OFF_GX;
    for (int d = d0; d < d1; ++d) s = fmaf(in_w[d*64 + i], in_b[d], s);
  } else if (t < OFF_WY) {
    if (t == OFF_G0) { for (int d = d0; d < d1; ++d) s = fmaf(in_b[d], in_b[d], s); }
  } else if (t < OFF_WU) {
    const int r = t - OFF_WY, l = r >> 11, qq = r & 2047, c = qq >> 5, n = qq & 31;
    for (int d = d0; d < d1; ++d)
      s = fmaf(Bw[(l*NS + n)*DM + d] * nsc[l*DM + d], in_w[d*64 + c], s);
  } else if (t < OFF_P) {
    const int r = t - OFF_WU, l = r >> 11, qq = r & 2047, c = qq >> 5, n = qq & 31;
    for (int d = d0; d < d1; ++d)
      s = fmaf(Cw[(l*DM + d)*NS + n], in_w[d*64 + c], s);
  } else if (t < OFF_R) {
    const int r = t - OFF_P, pi = r >> 10, qq = r & 1023, np = qq >> 5, n = qq & 31;
    const int m = pm6[pi], lp = pl6[pi];
    for (int d = d0; d < d1; ++d)
      s = fmaf(Bw[(m*NS + n)*DM + d] * nsc[m*DM + d], Cw[(lp*DM + d)*NS + np], s);
  } else if (t < OFF_CY) {
    const int r = t - OFF_R, ri = r >> 10, qq = r & 1023, np = qq >> 5, n = qq & 31;
    const int m = rm10[ri], lp = rl10[ri];
    for (int d = d0; d < d1; ++d)
      s = fmaf(Cw[(m*DM + d)*NS + n], Cw[(lp*DM + d)*NS + np], s);
  } else if (t < OFF_CU) {
    const int r = t - OFF_CY, l = r >> 5, n = r & 31;
    for (int d = d0; d < d1; ++d) {
      float bs = in_b[d];
      for (int lp = 0; lp < l; ++lp) bs += Cb[lp*DM + d];
      s = fmaf(Bw[(l*NS + n)*DM + d] * nsc[l*DM + d], bs, s);
    }
  } else if (t < OFF_TX) {
    const int r = t - OFF_CU, l = r >> 5, n = r & 31;
    for (int d = d0; d < d1; ++d) {
      float bs = in_b[d];
      for (int lp = 0; lp < l; ++lp) bs += Cb[lp*DM + d];
      s = fmaf(Cw[(l*DM + d)*NS + n], bs, s);
    }
  } else if (t < OFF_TV) {
    const int r = t - OFF_TX, l = r >> 6, i = r & 63;
    for (int d = d0; d < d1; ++d) s = fmaf(Cb[l*DM + d], in_w[d*64 + i], s);
  } else if (t < OFF_CT) {
    const int r = t - OFF_TV, vi = r >> 5, np = r & 31;
    const int m = rm10[vi], lp = rl10[vi];
    for (int d = d0; d < d1; ++d)
      s = fmaf(Cb[m*DM + d], Cw[(lp*DM + d)*NS + np], s);
  } else if (t < OFF_CC) {
    const int l = t - OFF_CT;
    for (int d = d0; d < d1; ++d) {
      float bs = in_b[d];
      for (int lp = 0; lp < l; ++lp) bs += Cb[lp*DM + d];
      s = fmaf(Cb[l*DM + d], bs, s);
    }
  } else if (t < OFF_AV) {
    const int l = t - OFF_CC;
    for (int d = d0; d < d1; ++d) s = fmaf(Cb[l*DM + d], Cb[l*DM + d], s);
  } else {
    s = (piece == 0) ? 1.0f / (1.0f + expf(-logA[t - OFF_AV])) : 0.f;
  }
  s += __shfl_xor(s, 1, 64);
  s += __shfl_xor(s, 2, 64);
  if (piece != 0) return;
  Wf[t] = s;

  // ---- direct fragment packing (inverse of the old packfrag mapping) ----
  if (t < OFF_GX) {                      // G [64][64]
    const int kk = t >> 6, n = t & 63;
    const int u = (kk >> 5)*4 + (n >> 4);
    const int lane = (((kk & 31) >> 3) << 4) + (n & 15);
    FrH[(u*256 + lane*4 + ((kk & 7) >> 1))*2 + (kk & 1)] = f2h(s);
  } else if (t >= OFF_WY && t < OFF_WU) {   // WY [4][64][32]
    const int r = t - OFF_WY, l = r >> 11, kk = (r & 2047) >> 5, n = r & 31;
    const int u = 8 + l*4 + (kk >> 5)*2 + (n >> 4);
    const int lane = (((kk & 31) >> 3) << 4) + (n & 15);
    FrH[(u*256 + lane*4 + ((kk & 7) >> 1))*2 + (kk & 1)] = f2h(s);
  } else if (t >= OFF_WU && t < OFF_P) {    // WU [4][64][32]
    const int r = t - OFF_WU, l = r >> 11, kk = (r & 2047) >> 5, n = r & 31;
    const int u = 24 + l*4 + (kk >> 5)*2 + (n >> 4);
    const int lane = (((kk & 31) >> 3) << 4) + (n & 15);
    FrH[(u*256 + lane*4 + ((kk & 7) >> 1))*2 + (kk & 1)] = f2h(s);
  } else if (t >= OFF_P && t < OFF_R) {     // P [6][32][32]
    const int r = t - OFF_P, pi = r >> 10, kk = (r & 1023) >> 5, n = r & 31;
    const int u = 40 + pi*2 + (n >> 4);
    const int lane = ((kk >> 3) << 4) + (n & 15);
    FrH[(u*256 + lane*4 + ((kk & 7) >> 1))*2 + (kk & 1)] = f2h(s);
  } else if (t >= OFF_R && t < OFF_CY) {    // R [10][32][32], self x0.5
    const int r = t - OFF_R, ri = r >> 10, kk = (r & 1023) >> 5, n = r & 31;
    const int u = 52 + ri*2 + (n >> 4);
    const int lane = ((kk >> 3) << 4) + (n & 15);
    const float sc = (ri == 0 || ri == 2 || ri == 5 || ri == 9) ? 0.5f : 1.f;
    FrH[(u*256 + lane*4 + ((kk & 7) >> 1))*2 + (kk & 1)] = f2h(s * sc);
  } else if (t >= OFF_TX && t < OFF_TV) {   // TX packed pairs
    const int r = t - OFF_TX, l = r >> 6, i = r & 63;
    FrH[(TXOFF + l*32 + (i >> 1))*2 + (i & 1)] = f2h(s);
  } else if (t >= OFF_TV && t < OFF_CT) {   // TV packed pairs
    const int r = t - OFF_TV, vi = r >> 5, nn = r & 31;
    FrH[(TVOFF + vi*16 + (nn >> 1))*2 + (nn & 1)] = f2h(s);
  }
}

// ---------------------------------------------------------------------------
// Per-layer body: Y MFMA -> D write (slot L) -> in-place scan -> U MFMA -> nq.
// 3 Mtiles per wave (rows wid*48 .. wid*48+47).
// ---------------------------------------------------------------------------
template<int L>
__device__ __forceinline__ void layer_mfma(
    const int tid, const int lane, const int wid, const int s0base,
    uint* lds, const float* __restrict__ Wf, const uint* __restrict__ Fr,
    const float* __restrict__ Bb,
    const uv4 (&xf)[3][2], uv4 (&sf0)[3], uv4 (&sf1)[3], uv4 (&sf2)[3], uv4 (&sf3)[3])
{
  constexpr int RB = L * (L + 1) / 2;
  constexpr int PB = (L == 1) ? 0 : (L == 2) ? 1 : 3;
  constexpr int SL = LS0 + L * 3264;
  float*  ldsF = (float*)lds;
  ushort* ldsH = (ushort*)lds;
  const int li = lane & 15, q4 = (lane >> 4) & 3;

  float cy[2], bb2[2], cu[2], tvs[2];
  #pragma unroll
  for (int nt = 0; nt < 2; ++nt) {
    const int nn = nt*16 + li;
    cy[nt]  = Wf[OFF_CY + L*32 + nn];
    bb2[nt] = Bb[L*32 + nn];
    cu[nt]  = Wf[OFF_CU + L*32 + nn];
    tvs[nt] = Wf[OFF_TV + (RB + L)*32 + nn];
  }
  float invv[3][4];
  #pragma unroll
  for (int m = 0; m < 3; ++m)
    #pragma unroll
    for (int r = 0; r < 4; ++r) {
      const int tk = wid*48 + m*16 + q4*4 + r;
      invv[m][r] = 1.0f / (sqrtf(fmaxf(ldsF[LNQ + tk], 0.f)) * 0.0625f + 1e-8f);
    }

  // ---- Y phase + D write (into slot L) ----
  #pragma unroll
  for (int nt = 0; nt < 2; ++nt) {
    const uv4 by0 = ldB(Fr, 8 + L*4 + 0*2 + nt, lane);
    const uv4 by1 = ldB(Fr, 8 + L*4 + 1*2 + nt, lane);
    uv4 bp0, bp1, bp2;
    if constexpr (L > 0) bp0 = ldB(Fr, 40 + (PB + 0)*2 + nt, lane);
    if constexpr (L > 1) bp1 = ldB(Fr, 40 + (PB + 1)*2 + nt, lane);
    if constexpr (L > 2) bp2 = ldB(Fr, 40 + (PB + 2)*2 + nt, lane);
    #pragma unroll
    for (int m = 0; m < 3; ++m) {
      f32x4 c = {cy[nt], cy[nt], cy[nt], cy[nt]};
      c = MF(xf[m][0], by0, c);
      c = MF(xf[m][1], by1, c);
      if constexpr (L > 0) c = MF(sf0[m], bp0, c);
      if constexpr (L > 1) c = MF(sf1[m], bp1, c);
      if constexpr (L > 2) c = MF(sf2[m], bp2, c);
      #pragma unroll
      for (int r = 0; r < 4; ++r) {
        const int tk = wid*48 + m*16 + q4*4 + r;
        const bool valid = (s0base > 0) || (tk >= NWARM);
        const float v = valid ? fmaf(invv[m][r], c[r], bb2[nt]) : 0.f;
        ldsH[SL*2 + tk*34 + nt*16 + li] = f2h(v);
      }
    }
  }
  __syncthreads();   // B1: D visible

  // ---- in-place scan: 8 groups of 24 tokens; stage-1 regs then Horner ----
  const int n = tid & 31, g = tid >> 5;
  const float a = Wf[OFF_AV + L*32 + n];
  float dv[HIST + 24];
  #pragma unroll
  for (int k = 0; k < HIST + 24; ++k) {
    const int p = g*24 - HIST + k;
    dv[k] = (p >= 0) ? h2f(ldsH[SL*2 + p*34 + n]) : 0.f;
  }
  __syncthreads();   // B2: all D reads complete before s overwrites

  {
    float carry = 0.f;
    #pragma unroll
    for (int k = 0; k < HIST + 24; ++k) {
      carry = fmaf(a, carry, dv[k]);
      if (k >= HIST) ldsH[SL*2 + (g*24 + k - HIST)*34 + n] = f2h(carry);
    }
  }
  // ---- tl per token (x + slots lp<L; none touches slot L) ----
  if (tid < PIPE) {
    float tl = Wf[OFF_CT + L];
    const uint* xr = lds + LX + tid*34;
    #pragma unroll 8
    for (int c2 = 0; c2 < 32; ++c2) tl = fdot2h(Fr[TXOFF + L*32 + c2], xr[c2], tl);
    if constexpr (L > 0) { const uint* sr = lds + LS0 + 0*3264 + tid*17;
      #pragma unroll
      for (int m2 = 0; m2 < 16; ++m2) tl = fdot2h(Fr[TVOFF + (RB+0)*16 + m2], sr[m2], tl); }
    if constexpr (L > 1) { const uint* sr = lds + LS0 + 1*3264 + tid*17;
      #pragma unroll
      for (int m2 = 0; m2 < 16; ++m2) tl = fdot2h(Fr[TVOFF + (RB+1)*16 + m2], sr[m2], tl); }
    if constexpr (L > 2) { const uint* sr = lds + LS0 + 2*3264 + tid*17;
      #pragma unroll
      for (int m2 = 0; m2 < 16; ++m2) tl = fdot2h(Fr[TVOFF + (RB+2)*16 + m2], sr[m2], tl); }
    ldsF[LTL + tid] = tl;
  }
  __syncthreads();   // B3: s + tl visible

  // ---- load S_L A-frags ----
  uv4 sA[3];
  #pragma unroll
  for (int m = 0; m < 3; ++m) {
    const uint* p = lds + SL + (wid*48 + m*16 + li)*17 + q4*4;
    uv4 v; v[0] = p[0]; v[1] = p[1]; v[2] = p[2]; v[3] = p[3];
    sA[m] = v;
  }
  if constexpr (L == 0)      { sf0[0] = sA[0]; sf0[1] = sA[1]; sf0[2] = sA[2]; }
  else if constexpr (L == 1) { sf1[0] = sA[0]; sf1[1] = sA[1]; sf1[2] = sA[2]; }
  else if constexpr (L == 2) { sf2[0] = sA[0]; sf2[1] = sA[1]; sf2[2] = sA[2]; }
  else                       { sf3[0] = sA[0]; sf3[1] = sA[1]; sf3[2] = sA[2]; }

  // ---- U/ACC phase + w row-dot ----
  float wv[3][4] = {{0,0,0,0},{0,0,0,0},{0,0,0,0}};
  #pragma unroll
  for (int nt = 0; nt < 2; ++nt) {
    const uv4 bu0 = ldB(Fr, 24 + L*4 + 0*2 + nt, lane);
    const uv4 bu1 = ldB(Fr, 24 + L*4 + 1*2 + nt, lane);
    uv4 br0, br1, br2;
    if constexpr (L > 0) br0 = ldB(Fr, 52 + (RB + 0)*2 + nt, lane);
    if constexpr (L > 1) br1 = ldB(Fr, 52 + (RB + 1)*2 + nt, lane);
    if constexpr (L > 2) br2 = ldB(Fr, 52 + (RB + 2)*2 + nt, lane);
    const uv4 brS = ldB(Fr, 52 + (RB + L)*2 + nt, lane);   // 0.5*R_self
    #pragma unroll
    for (int m = 0; m < 3; ++m) {
      f32x4 c = {0.f, 0.f, 0.f, 0.f};
      c = MF(xf[m][0], bu0, c);
      c = MF(xf[m][1], bu1, c);
      if constexpr (L > 0) c = MF(sf0[m], br0, c);
      if constexpr (L > 1) c = MF(sf1[m], br1, c);
      if constexpr (L > 2) c = MF(sf2[m], br2, c);
      c = MF(sA[m], brS, c);
      #pragma unroll
      for (int r = 0; r < 4; ++r) {
        const int tk = wid*48 + m*16 + q4*4 + r;
        const float sv = h2f(ldsH[SL*2 + tk*34 + nt*16 + li]);
        wv[m][r] = fmaf(c[r] + cu[nt] + tvs[nt], sv, wv[m][r]);
      }
    }
  }
  #pragma unroll
  for (int m = 0; m < 3; ++m)
    #pragma unroll
    for (int r = 0; r < 4; ++r) {
      float v = wv[m][r];
      v += __shfl_xor(v, 1, 64); v += __shfl_xor(v, 2, 64);
      v += __shfl_xor(v, 4, 64); v += __shfl_xor(v, 8, 64);
      wv[m][r] = v;
    }
  if (li == 0) {
    #pragma unroll
    for (int m = 0; m < 3; ++m)
      #pragma unroll
      for (int r = 0; r < 4; ++r) {
        const int tk = wid*48 + m*16 + q4*4 + r;
        ldsF[LNQ + tk] += 2.f * (wv[m][r] + ldsF[LTL + tk]);
      }
  }
  __syncthreads();   // B4: nq updated
}

// ---------------------------------------------------------------------------
// Main kernel (MFMA engine; grid 512 = exactly 2 blocks/CU).
// ---------------------------------------------------------------------------
__global__ __launch_bounds__(NTHR, 2) void ssm_main(
    const float* __restrict__ x, const float* __restrict__ Wf,
    const uint* __restrict__ Fr, const float* __restrict__ Bb,
    float* __restrict__ part)
{
  extern __shared__ uint lds[];
  float*  ldsF = (float*)lds;
  ushort* ldsH = (ushort*)lds;
  const int tid = threadIdx.x;
  const int lane = tid & 63, wid = tid >> 6;
  const int li = lane & 15, q4 = (lane >> 4) & 3;
  const int blk = blockIdx.x;
  const int bb = blk >> 6;                 // 64 chunks per sequence
  const int s0base = (blk & 63) * TOUT;

  // ---- stage x -> fp16 LDS rows [192][34] ----
  {
    const float4* xg4 = (const float4*)(x + (size_t)bb * S_ * DIN);
    #pragma unroll
    for (int k = 0; k < 12; ++k) {
      const int idx = k * NTHR + tid;
      const int tok = idx >> 4, c4 = idx & 15;
      const int lt = s0base - NWARM + tok;
      float4 v = make_float4(0.f, 0.f, 0.f, 0.f);
      if (lt >= 0) v = xg4[lt * 16 + c4];
      lds[LX + tok*34 + 2*c4]     = pack2(v.x, v.y);
      lds[LX + tok*34 + 2*c4 + 1] = pack2(v.z, v.w);
    }
  }
  __syncthreads();

  // ---- X A-frags (resident) ----
  uv4 xf[3][2];
  #pragma unroll
  for (int m = 0; m < 3; ++m)
    #pragma unroll
    for (int k = 0; k < 2; ++k) {
      const uint* p = lds + LX + (wid*48 + m*16 + li)*34 + k*16 + q4*4;
      uv4 v; v[0] = p[0]; v[1] = p[1]; v[2] = p[2]; v[3] = p[3];
      xf[m][k] = v;
    }

  // ---- nq0 = g0 + 2 gx.x + x^T G x ----
  {
    float val[3][4] = {{0,0,0,0},{0,0,0,0},{0,0,0,0}};
    #pragma unroll
    for (int nt = 0; nt < 4; ++nt) {
      const float gxv = 2.f * Wf[OFF_GX + nt*16 + li];
      const uv4 bg0 = ldB(Fr, 0*4 + nt, lane);
      const uv4 bg1 = ldB(Fr, 1*4 + nt, lane);
      #pragma unroll
      for (int m = 0; m < 3; ++m) {
        f32x4 c = {gxv, gxv, gxv, gxv};
        c = MF(xf[m][0], bg0, c);
        c = MF(xf[m][1], bg1, c);
        #pragma unroll
        for (int r = 0; r < 4; ++r) {
          const int tk = wid*48 + m*16 + q4*4 + r;
          const float xv = h2f(ldsH[tk*68 + nt*16 + li]);
          val[m][r] = fmaf(c[r], xv, val[m][r]);
        }
      }
    }
    const float g0 = Wf[OFF_G0];
    #pragma unroll
    for (int m = 0; m < 3; ++m)
      #pragma unroll
      for (int r = 0; r < 4; ++r) {
        float v = val[m][r];
        v += __shfl_xor(v, 1, 64); v += __shfl_xor(v, 2, 64);
        v += __shfl_xor(v, 4, 64); v += __shfl_xor(v, 8, 64);
        if (li == 0) ldsF[LNQ + wid*48 + m*16 + q4*4 + r] = g0 + v;
      }
  }
  __syncthreads();

  // ---- layers ----
  uv4 sf0[3], sf1[3], sf2[3], sf3[3];
  layer_mfma<0>(tid, lane, wid, s0base, lds, Wf, Fr, Bb, xf, sf0, sf1, sf2, sf3);
  layer_mfma<1>(tid, lane, wid, s0base, lds, Wf, Fr, Bb, xf, sf0, sf1, sf2, sf3);
  layer_mfma<2>(tid, lane, wid, s0base, lds, Wf, Fr, Bb, xf, sf0, sf1, sf2, sf3);
  layer_mfma<3>(tid, lane, wid, s0base, lds, Wf, Fr, Bb, xf, sf0, sf1, sf2, sf3);

  // ---- final r + block partial sums (6 narrow passes over dead x region) ----
  float rr = 0.f;
  if (tid >= NWARM && tid < PIPE)
    rr = 1.0f / (sqrtf(fmaxf(ldsF[LNQ + tid], 0.f)) * 0.0625f + 1e-8f);
  const int jj = tid - NWARM;             // 0..127 for output tokens
  float* pf = (float*)lds;                // overlays x (dead)

  // pass A1: [r | x0..31 * r]
  if (tid >= NWARM && tid < PIPE) {
    pf[jj*33] = rr;
    const float4* xr4 = (const float4*)(x + ((size_t)bb * S_ + (size_t)(s0base + jj)) * DIN);
    #pragma unroll
    for (int c4 = 0; c4 < 8; ++c4) {
      const float4 v = xr4[c4];
      pf[jj*33 + 1 + 4*c4] = v.x * rr; pf[jj*33 + 2 + 4*c4] = v.y * rr;
      pf[jj*33 + 3 + 4*c4] = v.z * rr; pf[jj*33 + 4 + 4*c4] = v.w * rr;
    }
  }
  __syncthreads();
  if (tid < 33) { float s = 0.f;
    for (int k = 0; k < TOUT; ++k) s += pf[k*33 + tid];
    part[blk*193 + tid] = s; }
  __syncthreads();
  // pass A2: x32..63 * r
  if (tid >= NWARM && tid < PIPE) {
    const float4* xr4 = (const float4*)(x + ((size_t)bb * S_ + (size_t)(s0base + jj)) * DIN);
    #pragma unroll
    for (int c4 = 8; c4 < 16; ++c4) {
      const float4 v = xr4[c4];
      const int o = 4*c4 - 32;
      pf[jj*33 + o]     = v.x * rr; pf[jj*33 + o + 1] = v.y * rr;
      pf[jj*33 + o + 2] = v.z * rr; pf[jj*33 + o + 3] = v.w * rr;
    }
  }
  __syncthreads();
  if (tid < 32) { float s = 0.f;
    for (int k = 0; k < TOUT; ++k) s += pf[k*33 + tid];
    part[blk*193 + 33 + tid] = s; }
  __syncthreads();
  // passes B..E: s_l * r
  for (int l = 0; l < 4; ++l) {
    if (tid >= NWARM && tid < PIPE) {
      #pragma unroll
      for (int m2 = 0; m2 < 16; ++m2) {
        const uint w = lds[LS0 + l*3264 + tid*17 + m2];
        pf[jj*33 + 2*m2]     = h2f((ushort)(w & 0xffffu)) * rr;
        pf[jj*33 + 2*m2 + 1] = h2f((ushort)(w >> 16)) * rr;
      }
    }
    __syncthreads();
    if (tid < 32) { float s = 0.f;
      for (int k = 0; k < TOUT; ++k) s += pf[k*33 + tid];
      part[blk*193 + 65 + l*32 + tid] = s; }
    __syncthreads();
  }
}

// ---------------------------------------------------------------------------
// Final: reduce partials (64 rows/batch, 4-way ILP), mean, classifier MLP.
// ---------------------------------------------------------------------------
__global__ __launch_bounds__(256) void ssm_final(
    const float* __restrict__ part,
    const float* __restrict__ in_w, const float* __restrict__ in_b,
    const float* __restrict__ Cw, const float* __restrict__ Cb,
    const float* __restrict__ fsc,
    const float* __restrict__ w1, const float* __restrict__ b1,
    const float* __restrict__ w2, const float* __restrict__ b2,
    float* __restrict__ out)
{
  const int b = blockIdx.x, t = threadIdx.x;
  __shared__ float red[193];
  __shared__ float meanv[DM];
  __shared__ float h1[DM];
  if (t < 193) {
    float a0 = 0.f, a1 = 0.f, a2 = 0.f, a3 = 0.f;
    const float* pp = part + (size_t)b * 64 * 193 + t;
    for (int k = 0; k < 64; k += 4) {
      a0 += pp[(k + 0) * 193]; a1 += pp[(k + 1) * 193];
      a2 += pp[(k + 2) * 193]; a3 += pp[(k + 3) * 193];
    }
    red[t] = (a0 + a1) + (a2 + a3);
  }
  __syncthreads();
  {
    const float rho = red[0];
    float m = in_b[t] * rho;
    #pragma unroll 4
    for (int i = 0; i < 64; ++i) m = fmaf(in_w[t*64 + i], red[1 + i], m);
    for (int l = 0; l < NL; ++l) {
      #pragma unroll 4
      for (int n = 0; n < 32; ++n)
        m = fmaf(Cw[(l*DM + t)*NS + n], red[65 + l*32 + n], m);
      m = fmaf(Cb[l*DM + t], rho, m);
    }
    meanv[t] = fsc[t] * m * (1.0f / (float)S_);
  }
  __syncthreads();
  {
    float z = b1[t];
    for (int e = 0; e < DM; ++e) z = fmaf(w1[t*DM + e], meanv[e], z);
    h1[t] = z / (1.0f + expf(-z));
  }
  __syncthreads();
  if (t < 10) {
    float lg = b2[t];
    for (int e = 0; e < DM; ++e) lg = fmaf(w2[t*DM + e], h1[e], lg);
    out[b*10 + t] = lg;
  }
}

// ---------------------------------------------------------------------------
extern "C" void kernel_launch(void* const* d_in, const int* in_sizes, int n_in,
                              void* d_out, int out_size, void* d_ws, size_t ws_size,
                              hipStream_t stream)
{
  const float* x    = (const float*)d_in[0];
  const float* in_w = (const float*)d_in[1];
  const float* in_b = (const float*)d_in[2];
  const float* logA = (const float*)d_in[3];
  const float* Bw   = (const float*)d_in[4];
  const float* Bb   = (const float*)d_in[5];
  const float* Cw   = (const float*)d_in[6];
  const float* Cb   = (const float*)d_in[7];
  const float* nsc  = (const float*)d_in[8];
  const float* fsc  = (const float*)d_in[9];
  const float* w1   = (const float*)d_in[10];
  const float* b1   = (const float*)d_in[11];
  const float* w2   = (const float*)d_in[12];
  const float* b2   = (const float*)d_in[13];
  float* out  = (float*)d_out;
  float* wsf  = (float*)d_ws;
  uint*  Fr   = (uint*)(wsf + WS_FRAG);
  float* part = wsf + WS_PART;
  (void)in_sizes; (void)n_in; (void)out_size; (void)ws_size;

  ssm_prep<<<(PRE_N * 4 + 255) / 256, 256, 0, stream>>>(in_w, in_b, logA, Bw, Cw, Cb,
                                                        nsc, wsf, (ushort*)Fr);
  ssm_main<<<NBLK, NTHR, LDSN * sizeof(uint), stream>>>(x, wsf, Fr, Bb, part);
  ssm_final<<<B_, 256, 0, stream>>>(part, in_w, in_b, Cw, Cb, fsc, w1, b1, w2, b2, out);
}